// Round 5
// baseline (699.228 us; speedup 1.0000x reference)
//
#include <hip/hip_runtime.h>
#include <hip/hip_bf16.h>
#include <cstdint>
#include <cstddef>

typedef __bf16 bf16_t;
typedef __bf16 bf16x8 __attribute__((ext_vector_type(8)));
typedef __bf16 bf16x4 __attribute__((ext_vector_type(4)));
typedef float  f32x4  __attribute__((ext_vector_type(4)));

#define D_MODEL 1024
#define SEQ     2048
#define NHEADS  16
#define DHEAD   64
#define DFF     4096

// async global->LDS, 16B per lane; lds base must be wave-uniform (dest = base + lane*16)
__device__ __forceinline__ void async_ld16(void* lds, const void* g) {
    __builtin_amdgcn_global_load_lds(
        (__attribute__((address_space(1))) void*)(void*)(g),
        (__attribute__((address_space(3))) void*)(lds), 16, 0, 0);
}

// Resident-operand XCD swizzle: XCD x owns by-chunk [x*cy, (x+1)*cy) which
// stays L2-resident; bx sweeps. Requires gridDim.y % 8 == 0 (bijective).
__device__ __forceinline__ void xcd_swizzle(int& bx, int& by) {
    const int gy = gridDim.y;
    const int i = blockIdx.x + gridDim.x * blockIdx.y;
    if ((gy & 7) == 0) {
        const int cy = gy >> 3;
        const int xcd = i & 7, j = i >> 3;
        bx = j / cy;
        by = xcd * cy + (j % cy);
    } else { bx = blockIdx.x; by = blockIdx.y; }
}

// ---------------------------------------------------------------------------
// fp32 (K x N) -> bf16 transposed; dst row for source col n:
//   (n>>4)*gstride + (n&15) + goff
// ---------------------------------------------------------------------------
__global__ __launch_bounds__(256)
void transpose_cast_kernel(const float* __restrict__ src, bf16_t* __restrict__ dst,
                           int K, int N, int gstride, int goff)
{
    __shared__ float tile[32][33];
    const int bn = blockIdx.x * 32, bk = blockIdx.y * 32;
    const int tx = threadIdx.x & 31, ty = threadIdx.x >> 5;
#pragma unroll
    for (int i = 0; i < 32; i += 8)
        tile[ty + i][tx] = src[(size_t)(bk + ty + i) * N + bn + tx];
    __syncthreads();
#pragma unroll
    for (int i = 0; i < 32; i += 8) {
        const int n = bn + ty + i, kk = bk + tx;
        const int row = (n >> 4) * gstride + (n & 15) + goff;
        dst[(size_t)row * K + kk] = (bf16_t)tile[tx][ty + i];
    }
}

// ---------------------------------------------------------------------------
// bf16 V [bh][s][dh] -> vT tiled [bh][kc=s/8][dh][8] (so attn V-staging is a
// LINEAR global_load_lds stream).
// ---------------------------------------------------------------------------
__global__ __launch_bounds__(256)
void transpose_v_kernel(const bf16_t* __restrict__ v, bf16_t* __restrict__ vt)
{
    __shared__ bf16_t T[64 * 66];
    const int bh = blockIdx.y, s0 = blockIdx.x * 64;
    const int tid = threadIdx.x;
    const size_t vb = (size_t)bh * SEQ * DHEAD;
#pragma unroll
    for (int h = 0; h < 2; ++h) {
        const int s = h * 32 + (tid >> 3), dc = (tid & 7) * 8;
        const bf16x8 vv = *(const bf16x8*)(v + vb + (size_t)(s0 + s) * DHEAD + dc);
#pragma unroll
        for (int j = 0; j < 8; ++j) T[(dc + j) * 66 + s] = vv[j];
    }
    __syncthreads();
    const size_t tb = (size_t)bh * DHEAD * SEQ;
    const uint32_t* Tw = (const uint32_t*)T;
#pragma unroll
    for (int h = 0; h < 2; ++h) {
        const int dh = h * 32 + (tid >> 3), kc = (tid & 7) * 8;
        uint4 o;
        o.x = Tw[dh * 33 + kc / 2 + 0];
        o.y = Tw[dh * 33 + kc / 2 + 1];
        o.z = Tw[dh * 33 + kc / 2 + 2];
        o.w = Tw[dh * 33 + kc / 2 + 3];
        // tiled dst: [kcg][dh][8], kcg = (s0+kc)/8
        *(uint4*)(vt + tb + (size_t)((s0 + kc) >> 3) * 512 + dh * 8) = o;
    }
}

// ---------------------------------------------------------------------------
// RMSNorm: fp32 row (1024) -> bf16 row
// ---------------------------------------------------------------------------
__global__ __launch_bounds__(256)
void rmsnorm_kernel(const float* __restrict__ x, const float* __restrict__ gw,
                    bf16_t* __restrict__ out)
{
    const int row = blockIdx.x, tid = threadIdx.x;
    const float4 v = ((const float4*)(x + (size_t)row * D_MODEL))[tid];
    float ss = v.x*v.x + v.y*v.y + v.z*v.z + v.w*v.w;
#pragma unroll
    for (int d = 1; d < 64; d <<= 1) ss += __shfl_xor(ss, d);
    __shared__ float red[4];
    if ((tid & 63) == 0) red[tid >> 6] = ss;
    __syncthreads();
    const float tot = red[0] + red[1] + red[2] + red[3];
    const float sc = rsqrtf(tot * (1.f / D_MODEL) + 1e-5f);
    const float4 gv = ((const float4*)gw)[tid];
    bf16x4 o;
    o[0] = (bf16_t)(v.x * sc * gv.x);
    o[1] = (bf16_t)(v.y * sc * gv.y);
    o[2] = (bf16_t)(v.z * sc * gv.z);
    o[3] = (bf16_t)(v.w * sc * gv.w);
    ((bf16x4*)(out + (size_t)row * D_MODEL))[tid] = o;
}

// ---------------------------------------------------------------------------
// 256x256 GEMM, coalesced staging + XOR-swizzled row-major LDS.
// (unchanged from round-4 winner)
// ---------------------------------------------------------------------------
template <int MODE>
__global__ __launch_bounds__(512, 2)
void gemm256_kernel(const bf16_t* __restrict__ A, const bf16_t* __restrict__ Bt,
                    int M, int N, int K,
                    bf16_t* __restrict__ qo, bf16_t* __restrict__ ko, bf16_t* __restrict__ vo,
                    bf16_t* __restrict__ gate)
{
    __shared__ bf16x8 lds[8192];   // 128 KB
    const int tid  = threadIdx.x;
    const int wave = tid >> 6;
    const int lane = tid & 63;
    const int r = lane & 15, g = lane >> 4;
    const int wm = wave >> 2;      // 2 M-waves
    const int wn = wave & 3;       // 4 N-waves
    const int r3 = (r >> 3) & 1;
    const int gx = g ^ (((r >> 2) & 1) << 1);
    const int cx0 = r3 * 4 + gx;       // chunk term ks=0
    const int cx1 = cx0 ^ 4;           // chunk term ks=1

    int bx, by;
    xcd_swizzle(bx, by);
    const int row0 = by * 256;
    const int col0 = bx * 256;

    const f32x4 fzero = {0.f, 0.f, 0.f, 0.f};
    f32x4 acc[8][4];
#pragma unroll
    for (int i = 0; i < 8; ++i)
#pragma unroll
        for (int j = 0; j < 4; ++j) acc[i][j] = fzero;

    const int kcx = ((tid & 7) ^ (((tid >> 5) & 1) << 1) ^ (((tid >> 6) & 1) << 2)) * 8;
    const bf16_t* aSrc = A  + (size_t)(row0 + (tid >> 3)) * K + kcx;
    const bf16_t* bSrc = Bt + (size_t)(col0 + (tid >> 3)) * K + kcx;

    const int aRB = wm * 1024 + r * 8;
    const int bRB = 2048 + (wn >> 1) * 1024 + ((wn & 1) * 64 + r) * 8;

#define STA(nb, ktn, h_, j_) \
    async_ld16(&lds[(nb) + (h_) * 1024 + (j_) * 512 + tid], \
               aSrc + (size_t)((h_) * 128 + (j_) * 64) * K + (ktn))
#define STB(nb, ktn, h_, j_) \
    async_ld16(&lds[(nb) + 2048 + (h_) * 1024 + (j_) * 512 + tid], \
               bSrc + (size_t)((h_) * 128 + (j_) * 64) * K + (ktn))

    STB(0, 0, 0, 0); STB(0, 0, 0, 1); STB(0, 0, 1, 0); STB(0, 0, 1, 1);
    STA(0, 0, 0, 0); STA(0, 0, 1, 0);
    STA(0, 0, 0, 1); STA(0, 0, 1, 1);
    asm volatile("s_waitcnt vmcnt(2)" ::: "memory");   // B + A-j0 confirmed
    __builtin_amdgcn_s_barrier();

    bf16x8 aF[8], bF[8];

    const int NT = K >> 6;
    for (int t = 0; t < NT; ++t) {
        const int AB  = (t & 1) << 12;
        const int nb  = AB ^ 4096;
        const int ktn = (t + 1) << 6;
        const bool pf = (t + 1) < NT;

        // ---- phase 0: quad (mh0, nh0) ----
#pragma unroll
        for (int q = 0; q < 4; ++q) {
            aF[q * 2 + 0] = lds[AB + aRB + q * 128 + cx0];
            aF[q * 2 + 1] = lds[AB + aRB + q * 128 + cx1];
        }
#pragma unroll
        for (int n = 0; n < 2; ++n) {
            bF[n * 2 + 0] = lds[AB + bRB + n * 128 + cx0];
            bF[n * 2 + 1] = lds[AB + bRB + n * 128 + cx1];
        }
        if (pf) { STB(nb, ktn, 0, 0); STB(nb, ktn, 0, 1); }
        __builtin_amdgcn_s_barrier();
        asm volatile("s_waitcnt lgkmcnt(0)" ::: "memory");
        __builtin_amdgcn_sched_barrier(0);
        __builtin_amdgcn_s_setprio(1);
#pragma unroll
        for (int q = 0; q < 4; ++q)
#pragma unroll
            for (int n = 0; n < 2; ++n)
#pragma unroll
                for (int ks = 0; ks < 2; ++ks)
                    acc[q][n] = __builtin_amdgcn_mfma_f32_16x16x32_bf16(
                        aF[q * 2 + ks], bF[n * 2 + ks], acc[q][n], 0, 0, 0);
        __builtin_amdgcn_s_setprio(0);
        __builtin_amdgcn_s_barrier();

        // ---- phase 1: quad (mh0, nh1) ----
#pragma unroll
        for (int n = 0; n < 2; ++n) {
            bF[4 + n * 2 + 0] = lds[AB + bRB + (32 + n * 16) * 8 + cx0];
            bF[4 + n * 2 + 1] = lds[AB + bRB + (32 + n * 16) * 8 + cx1];
        }
        if (pf) { STB(nb, ktn, 1, 0); STB(nb, ktn, 1, 1); }
        __builtin_amdgcn_s_barrier();
        asm volatile("s_waitcnt lgkmcnt(0)" ::: "memory");
        __builtin_amdgcn_sched_barrier(0);
        __builtin_amdgcn_s_setprio(1);
#pragma unroll
        for (int q = 0; q < 4; ++q)
#pragma unroll
            for (int n = 0; n < 2; ++n)
#pragma unroll
                for (int ks = 0; ks < 2; ++ks)
                    acc[q][2 + n] = __builtin_amdgcn_mfma_f32_16x16x32_bf16(
                        aF[q * 2 + ks], bF[4 + n * 2 + ks], acc[q][2 + n], 0, 0, 0);
        __builtin_amdgcn_s_setprio(0);
        if (pf) asm volatile("s_waitcnt vmcnt(4)" ::: "memory");
        else    asm volatile("s_waitcnt vmcnt(0)" ::: "memory");
        __builtin_amdgcn_s_barrier();

        // ---- phase 2: quad (mh1, nh1) ----
#pragma unroll
        for (int q = 0; q < 4; ++q) {
            aF[q * 2 + 0] = lds[AB + aRB + (64 + q * 16) * 8 + cx0];
            aF[q * 2 + 1] = lds[AB + aRB + (64 + q * 16) * 8 + cx1];
        }
        if (pf) { STA(nb, ktn, 0, 0); STA(nb, ktn, 1, 0); }
        __builtin_amdgcn_s_barrier();
        asm volatile("s_waitcnt lgkmcnt(0)" ::: "memory");
        __builtin_amdgcn_sched_barrier(0);
        __builtin_amdgcn_s_setprio(1);
#pragma unroll
        for (int q = 0; q < 4; ++q)
#pragma unroll
            for (int n = 0; n < 2; ++n)
#pragma unroll
                for (int ks = 0; ks < 2; ++ks)
                    acc[4 + q][2 + n] = __builtin_amdgcn_mfma_f32_16x16x32_bf16(
                        aF[q * 2 + ks], bF[4 + n * 2 + ks], acc[4 + q][2 + n], 0, 0, 0);
        __builtin_amdgcn_s_setprio(0);
        __builtin_amdgcn_s_barrier();

        // ---- phase 3: quad (mh1, nh0) ----
        if (pf) { STA(nb, ktn, 0, 1); STA(nb, ktn, 1, 1); }
        __builtin_amdgcn_s_barrier();
        __builtin_amdgcn_s_setprio(1);
#pragma unroll
        for (int q = 0; q < 4; ++q)
#pragma unroll
            for (int n = 0; n < 2; ++n)
#pragma unroll
                for (int ks = 0; ks < 2; ++ks)
                    acc[4 + q][n] = __builtin_amdgcn_mfma_f32_16x16x32_bf16(
                        aF[q * 2 + ks], bF[n * 2 + ks], acc[4 + q][n], 0, 0, 0);
        __builtin_amdgcn_s_setprio(0);
        if (pf) asm volatile("s_waitcnt vmcnt(2)" ::: "memory");
        __builtin_amdgcn_s_barrier();
    }
#undef STA
#undef STB

    const int mbase = row0 + wm * 128 + g * 4;
    const int nbase = col0 + wn * 64 + r;

    if constexpr (MODE == 2) {
#pragma unroll
        for (int np = 0; np < 2; ++np) {
            const int gc = (col0 >> 1) + wn * 32 + np * 16 + r;
#pragma unroll
            for (int mt = 0; mt < 8; ++mt) {
#pragma unroll
                for (int e = 0; e < 4; ++e) {
                    const float v1 = acc[mt][2 * np][e];
                    const float v3 = acc[mt][2 * np + 1][e];
                    const float sv = v1 * __builtin_amdgcn_rcpf(1.f + __expf(-v1));
                    const int grow = mbase + mt * 16 + e;
                    gate[(size_t)grow * DFF + gc] = (bf16_t)(sv * v3);
                }
            }
        }
    } else { // MODE 0
#pragma unroll
        for (int nt = 0; nt < 4; ++nt) {
            const int gcol = nbase + nt * 16;
            const int mat  = gcol >> 10;
            const int d    = gcol & 1023;
            const int head = d >> 6;
            const int dh   = d & 63;
            const float invf = __expf((float)(dh & ~1) * -0.14391157f);
            const size_t hb = (size_t)head * SEQ * DHEAD + dh;
#pragma unroll
            for (int mt = 0; mt < 8; ++mt) {
#pragma unroll
                for (int e = 0; e < 4; ++e) {
                    const float val = acc[mt][nt][e];
                    const float partner = __shfl_xor(val, 1);
                    const int grow = mbase + mt * 16 + e;
                    const int b = grow >> 11;
                    const int s = grow & 2047;
                    const size_t dst = (size_t)b * NHEADS * SEQ * DHEAD + hb + (size_t)s * DHEAD;
                    if (mat == 2) {
                        vo[dst] = (bf16_t)val;
                    } else {
                        float sn, cs;
                        __sincosf((float)s * invf, &sn, &cs);
                        const float rv = (dh & 1) ? (partner * sn + val * cs)
                                                  : (val * cs - partner * sn);
                        if (mat == 0) qo[dst] = (bf16_t)(rv * 0.125f);
                        else          ko[dst] = (bf16_t)rv;
                    }
                }
            }
        }
    }
}

// ---------------------------------------------------------------------------
// 128x128 GEMM (4 waves, 3 blocks/CU). (unchanged from round-4 winner)
// ---------------------------------------------------------------------------
template <int MODE>
__global__ __launch_bounds__(256, 3)
void gemm128_kernel(const bf16_t* __restrict__ A, const bf16_t* __restrict__ Bt,
                    int M, int N, int K, const float* res, float* outf)
{
    __shared__ bf16x8 Al[1024];
    __shared__ bf16x8 Bl[1024];
    const int tid  = threadIdx.x;
    const int wave = tid >> 6;
    const int lane = tid & 63;
    const int r    = lane & 15;
    const int g    = lane >> 4;
    const int wm   = wave >> 1;
    const int wn   = wave & 1;
    const int r3 = (r >> 3) & 1;
    const int gx = g ^ (((r >> 2) & 1) << 1);
    const int cx0 = r3 * 4 + gx;
    const int cx1 = cx0 ^ 4;

    int bx, by;
    xcd_swizzle(bx, by);
    const int row0 = by * 128;
    const int col0 = bx * 128;

    const f32x4 fzero = {0.f, 0.f, 0.f, 0.f};
    f32x4 acc[4][4];
#pragma unroll
    for (int i = 0; i < 4; ++i)
#pragma unroll
        for (int j = 0; j < 4; ++j) acc[i][j] = fzero;

    const int kcx = ((tid & 7) ^ (((tid >> 5) & 1) << 1) ^ (((tid >> 6) & 1) << 2)) * 8;
    const bf16_t* a0 = A  + (size_t)(row0 + (tid >> 3)) * K + kcx;
    const bf16_t* b0 = Bt + (size_t)(col0 + (tid >> 3)) * K + kcx;

    for (int kt = 0; kt < K; kt += 64) {
#pragma unroll
        for (int j = 0; j < 4; ++j)
            async_ld16(&Al[j * 256 + tid], a0 + kt + (size_t)(j * 32) * K);
#pragma unroll
        for (int j = 0; j < 4; ++j)
            async_ld16(&Bl[j * 256 + tid], b0 + kt + (size_t)(j * 32) * K);
        __syncthreads();
#pragma unroll
        for (int s = 0; s < 2; ++s) {
            const int cx = s ? cx1 : cx0;
            bf16x8 af[4], bfr[4];
#pragma unroll
            for (int mt = 0; mt < 4; ++mt) af[mt]  = Al[(wm * 64 + mt * 16 + r) * 8 + cx];
#pragma unroll
            for (int nt = 0; nt < 4; ++nt) bfr[nt] = Bl[(wn * 64 + nt * 16 + r) * 8 + cx];
#pragma unroll
            for (int mt = 0; mt < 4; ++mt)
#pragma unroll
                for (int nt = 0; nt < 4; ++nt)
                    acc[mt][nt] = __builtin_amdgcn_mfma_f32_16x16x32_bf16(
                        af[mt], bfr[nt], acc[mt][nt], 0, 0, 0);
        }
        __syncthreads();
    }

    const int mbase = row0 + wm * 64 + g * 4;
    const int nbase = col0 + wn * 64 + r;
#pragma unroll
    for (int mt = 0; mt < 4; ++mt) {
#pragma unroll
        for (int nt = 0; nt < 4; ++nt) {
#pragma unroll
            for (int e = 0; e < 4; ++e) {
                const int grow = mbase + mt * 16 + e;
                const int gcol = nbase + nt * 16;
                const size_t idx = (size_t)grow * D_MODEL + gcol;
                outf[idx] = res[idx] + acc[mt][nt][e];
            }
        }
    }
}

// ---------------------------------------------------------------------------
// Causal flash attention. q(pre-scaled)/k: [B,H,S,Dh]; vT tiled [kc][dh][8].
// KVBLK=64, LDS 32KB (K 512 + V 512 + P 4x256 chunks) -> 4 blocks/CU,
// 4 waves/SIMD. P layout [qrow][key ^ (g_w<<4)] -> 2-way (free) write banks.
// Wave-uniform skip of fully-masked tiles (no barrier inside guard).
// ---------------------------------------------------------------------------
__global__ __launch_bounds__(256, 4)
void attn_kernel(const bf16_t* __restrict__ qg, const bf16_t* __restrict__ kg,
                 const bf16_t* __restrict__ vT, bf16_t* __restrict__ ctx)
{
    __shared__ bf16x8 lds[2048];   // 32 KB: K[0,512) V[512,1024) P[1024,2048)
    const int qblk = (gridDim.x - 1) - blockIdx.x;
    const int bh   = blockIdx.y;
    const int tid  = threadIdx.x;
    const int wave = tid >> 6;
    const int lane = tid & 63;
    const int r = lane & 15, g = lane >> 4;
    const size_t base = (size_t)bh * SEQ * DHEAD;
    const int qw = qblk * 128 + wave * 32;

    bf16x8 qf[2][2];
#pragma unroll
    for (int rt = 0; rt < 2; ++rt)
#pragma unroll
        for (int kh = 0; kh < 2; ++kh)
            qf[rt][kh] = *(const bf16x8*)(qg + base + (size_t)(qw + rt*16 + r) * DHEAD + kh*32 + g*8);

    const f32x4 fzero = {0.f, 0.f, 0.f, 0.f};
    f32x4 O[2][4];
    float mi[2][4], li[2][4];
#pragma unroll
    for (int rt = 0; rt < 2; ++rt)
#pragma unroll
        for (int e = 0; e < 4; ++e) { mi[rt][e] = -1e30f; li[rt][e] = 0.f; }
#pragma unroll
    for (int rt = 0; rt < 2; ++rt)
#pragma unroll
        for (int d = 0; d < 4; ++d) O[rt][d] = fzero;

    bf16_t* const Pb = (bf16_t*)&lds[1024 + wave * 256];  // 32 qrows x 64 keys
    const int pcx = ((r >> 2) & 3) << 1;                   // read-side chunk XOR

    const int NKB = 2 * qblk + 2;
    for (int kb = 0; kb < NKB; ++kb) {
        const int k0 = kb * 64;
        // stage K: [dhc 8][key 64]; 2 instrs/lane, key-row coalesced
        {
            const bf16_t* kp = kg + base + (size_t)(k0 + lane) * DHEAD + wave * 8;
            async_ld16(&lds[tid], kp);
            async_ld16(&lds[256 + tid], kp + 32);
        }
        // stage V: tiled vT is linear here
        {
            const bf16_t* vp = vT + base + (size_t)k0 * DHEAD + tid * 8;
            async_ld16(&lds[512 + tid], vp);
            async_ld16(&lds[768 + tid], vp + 2048);
        }
        __syncthreads();

        if (k0 <= qw + 31) {   // wave-uniform: tile has >=1 unmasked key
            f32x4 sc[2][4];
            __builtin_amdgcn_s_setprio(1);
#pragma unroll
            for (int ct = 0; ct < 4; ++ct) {
                const bf16x8 kf0 = lds[g * 64 + ct * 16 + r];
                const bf16x8 kf1 = lds[(4 + g) * 64 + ct * 16 + r];
                sc[0][ct] = __builtin_amdgcn_mfma_f32_16x16x32_bf16(qf[0][0], kf0, fzero, 0, 0, 0);
                sc[0][ct] = __builtin_amdgcn_mfma_f32_16x16x32_bf16(qf[0][1], kf1, sc[0][ct], 0, 0, 0);
                sc[1][ct] = __builtin_amdgcn_mfma_f32_16x16x32_bf16(qf[1][0], kf0, fzero, 0, 0, 0);
                sc[1][ct] = __builtin_amdgcn_mfma_f32_16x16x32_bf16(qf[1][1], kf1, sc[1][ct], 0, 0, 0);
            }
            __builtin_amdgcn_s_setprio(0);
            if (k0 + 63 > qw) { // near-diagonal: causal mask
#pragma unroll
                for (int rt = 0; rt < 2; ++rt)
#pragma unroll
                    for (int ct = 0; ct < 4; ++ct)
#pragma unroll
                        for (int e = 0; e < 4; ++e)
                            if (k0 + ct * 16 + r > qw + rt * 16 + g * 4 + e)
                                sc[rt][ct][e] = -1e30f;
            }
#pragma unroll
            for (int rt = 0; rt < 2; ++rt) {
#pragma unroll
                for (int e = 0; e < 4; ++e) {
                    float mx = fmaxf(fmaxf(sc[rt][0][e], sc[rt][1][e]),
                                     fmaxf(sc[rt][2][e], sc[rt][3][e]));
#pragma unroll
                    for (int d = 1; d < 16; d <<= 1) mx = fmaxf(mx, __shfl_xor(mx, d));
                    const float mnew  = fmaxf(mi[rt][e], mx);
                    const float alpha = __expf(mi[rt][e] - mnew);
                    mi[rt][e] = mnew;
                    float pv[4], rs = 0.f;
#pragma unroll
                    for (int ct = 0; ct < 4; ++ct) { pv[ct] = __expf(sc[rt][ct][e] - mnew); rs += pv[ct]; }
#pragma unroll
                    for (int d = 1; d < 16; d <<= 1) rs += __shfl_xor(rs, d);
                    li[rt][e] = li[rt][e] * alpha + rs;
#pragma unroll
                    for (int dht = 0; dht < 4; ++dht) O[rt][dht][e] *= alpha;
                    const int qlocal = rt * 16 + g * 4 + e;
                    // P write: [qrow][key ^ (g<<4)] -> 2-way banks (free)
#pragma unroll
                    for (int ct = 0; ct < 4; ++ct)
                        Pb[qlocal * 64 + ((ct * 16 + r) ^ (g << 4))] = (bf16_t)pv[ct];
                }
            }
            __builtin_amdgcn_s_setprio(1);
#pragma unroll
            for (int kt = 0; kt < 2; ++kt) {
                const int cix = (kt * 4 + g) ^ pcx;
                const bf16x8 pf0 = lds[1024 + wave * 256 + r * 8 + cix];
                const bf16x8 pf1 = lds[1024 + wave * 256 + 128 + r * 8 + cix];
#pragma unroll
                for (int dht = 0; dht < 4; ++dht) {
                    const bf16x8 vf = lds[512 + (kt * 4 + g) * 64 + dht * 16 + r];
                    O[0][dht] = __builtin_amdgcn_mfma_f32_16x16x32_bf16(pf0, vf, O[0][dht], 0, 0, 0);
                    O[1][dht] = __builtin_amdgcn_mfma_f32_16x16x32_bf16(pf1, vf, O[1][dht], 0, 0, 0);
                }
            }
            __builtin_amdgcn_s_setprio(0);
        }
        __syncthreads();
    }

    const int b = bh >> 4, head = bh & 15;
#pragma unroll
    for (int rt = 0; rt < 2; ++rt) {
#pragma unroll
        for (int e = 0; e < 4; ++e) {
            const float inv = __builtin_amdgcn_rcpf(li[rt][e]);
            const int s = qw + rt * 16 + g * 4 + e;
            bf16_t* op = ctx + ((size_t)(b * SEQ + s)) * D_MODEL + head * DHEAD + r;
#pragma unroll
            for (int dht = 0; dht < 4; ++dht)
                op[dht * 16] = (bf16_t)(O[rt][dht][e] * inv);
        }
    }
}

// ---------------------------------------------------------------------------
extern "C" void kernel_launch(void* const* d_in, const int* in_sizes, int n_in,
                              void* d_out, int out_size, void* d_ws, size_t ws_size,
                              hipStream_t stream)
{
    (void)in_sizes; (void)n_in; (void)out_size; (void)ws_size;
    const float* x  = (const float*)d_in[0];
    const float* g1 = (const float*)d_in[2];
    const float* g2 = (const float*)d_in[3];
    const float* wq = (const float*)d_in[4];
    const float* wk = (const float*)d_in[5];
    const float* wv = (const float*)d_in[6];
    const float* wo = (const float*)d_in[7];
    const float* w1 = (const float*)d_in[8];
    const float* w2 = (const float*)d_in[9];
    const float* w3 = (const float*)d_in[10];
    float* out = (float*)d_out;
    char* ws = (char*)d_ws;
    const size_t MB = 1ull << 20;
    bf16_t* wqkvT = (bf16_t*)(ws + 0);        // 3072 x 1024
    bf16_t* woT   = (bf16_t*)(ws + 6  * MB);  // 1024 x 1024
    bf16_t* w13T  = (bf16_t*)(ws + 8  * MB);  // 8192 x 1024 (16-col-group ilv)
    bf16_t* w2T   = (bf16_t*)(ws + 24 * MB);  // 1024 x 4096
    bf16_t* hbuf  = (bf16_t*)(ws + 32 * MB);  // h / h2; reused as vT during attn
    bf16_t* qbuf  = (bf16_t*)(ws + 48 * MB);
    bf16_t* kbuf  = (bf16_t*)(ws + 64 * MB);
    bf16_t* vbuf  = (bf16_t*)(ws + 80 * MB);
    bf16_t* ctx   = (bf16_t*)(ws + 96 * MB);
    bf16_t* gate  = (bf16_t*)(ws + 48 * MB);  // 8192 x 4096, reuses q/k/v/ctx
    bf16_t* vTb   = hbuf;                     // tiled [bh][kc][dh][8]

    dim3 blk(256);
    dim3 blk5(512);
    transpose_cast_kernel<<<dim3(32, 32),  blk, 0, stream>>>(wq, wqkvT,             1024, 1024, 16, 0);
    transpose_cast_kernel<<<dim3(32, 32),  blk, 0, stream>>>(wk, wqkvT + 1024*1024, 1024, 1024, 16, 0);
    transpose_cast_kernel<<<dim3(32, 32),  blk, 0, stream>>>(wv, wqkvT + 2048*1024, 1024, 1024, 16, 0);
    transpose_cast_kernel<<<dim3(32, 32),  blk, 0, stream>>>(wo, woT,               1024, 1024, 16, 0);
    transpose_cast_kernel<<<dim3(128, 32), blk, 0, stream>>>(w1, w13T,              1024, 4096, 32, 0);
    transpose_cast_kernel<<<dim3(128, 32), blk, 0, stream>>>(w3, w13T,              1024, 4096, 32, 16);
    transpose_cast_kernel<<<dim3(32, 128), blk, 0, stream>>>(w2, w2T,               4096, 1024, 16, 0);

    rmsnorm_kernel<<<dim3(8192), blk, 0, stream>>>(x, g1, hbuf);

    gemm256_kernel<0><<<dim3(12, 32), blk5, 0, stream>>>(hbuf, wqkvT, 8192, 3072, 1024,
        qbuf, kbuf, vbuf, nullptr);

    transpose_v_kernel<<<dim3(32, 64), blk, 0, stream>>>(vbuf, vTb);

    attn_kernel<<<dim3(16, 64), blk, 0, stream>>>(qbuf, kbuf, vTb, ctx);

    gemm128_kernel<1><<<dim3(8, 64), blk, 0, stream>>>(ctx, woT, 8192, 1024, 1024, x, out);

    rmsnorm_kernel<<<dim3(8192), blk, 0, stream>>>(out, g2, hbuf);

    gemm256_kernel<2><<<dim3(32, 32), blk5, 0, stream>>>(hbuf, w13T, 8192, 8192, 1024,
        nullptr, nullptr, nullptr, gate);

    gemm128_kernel<3><<<dim3(8, 64), blk, 0, stream>>>(gate, w2T, 8192, 1024, 4096, out, out);
}

// Round 6
// 678.545 us; speedup vs baseline: 1.0305x; 1.0305x over previous
//
#include <hip/hip_runtime.h>
#include <hip/hip_bf16.h>
#include <cstdint>
#include <cstddef>

typedef __bf16 bf16_t;
typedef __bf16 bf16x8 __attribute__((ext_vector_type(8)));
typedef __bf16 bf16x4 __attribute__((ext_vector_type(4)));
typedef float  f32x4  __attribute__((ext_vector_type(4)));

#define D_MODEL 1024
#define SEQ     2048
#define NHEADS  16
#define DHEAD   64
#define DFF     4096

// async global->LDS, 16B per lane; lds base must be wave-uniform (dest = base + lane*16)
__device__ __forceinline__ void async_ld16(void* lds, const void* g) {
    __builtin_amdgcn_global_load_lds(
        (__attribute__((address_space(1))) void*)(void*)(g),
        (__attribute__((address_space(3))) void*)(lds), 16, 0, 0);
}

// Resident-operand XCD swizzle: XCD x owns by-chunk [x*cy, (x+1)*cy) which
// stays L2-resident; bx sweeps. Requires gridDim.y % 8 == 0 (bijective).
__device__ __forceinline__ void xcd_swizzle(int& bx, int& by) {
    const int gy = gridDim.y;
    const int i = blockIdx.x + gridDim.x * blockIdx.y;
    if ((gy & 7) == 0) {
        const int cy = gy >> 3;
        const int xcd = i & 7, j = i >> 3;
        bx = j / cy;
        by = xcd * cy + (j % cy);
    } else { bx = blockIdx.x; by = blockIdx.y; }
}

// ---------------------------------------------------------------------------
// fp32 (K x N) -> bf16 transposed; dst row for source col n:
//   (n>>4)*gstride + (n&15) + goff
// ---------------------------------------------------------------------------
__global__ __launch_bounds__(256)
void transpose_cast_kernel(const float* __restrict__ src, bf16_t* __restrict__ dst,
                           int K, int N, int gstride, int goff)
{
    __shared__ float tile[32][33];
    const int bn = blockIdx.x * 32, bk = blockIdx.y * 32;
    const int tx = threadIdx.x & 31, ty = threadIdx.x >> 5;
#pragma unroll
    for (int i = 0; i < 32; i += 8)
        tile[ty + i][tx] = src[(size_t)(bk + ty + i) * N + bn + tx];
    __syncthreads();
#pragma unroll
    for (int i = 0; i < 32; i += 8) {
        const int n = bn + ty + i, kk = bk + tx;
        const int row = (n >> 4) * gstride + (n & 15) + goff;
        dst[(size_t)row * K + kk] = (bf16_t)tile[tx][ty + i];
    }
}

// ---------------------------------------------------------------------------
// bf16 V [bh][s][dh] -> vT tiled [bh][kc=s/8][dh][8] (so attn V-staging is a
// LINEAR global_load_lds stream).
// ---------------------------------------------------------------------------
__global__ __launch_bounds__(256)
void transpose_v_kernel(const bf16_t* __restrict__ v, bf16_t* __restrict__ vt)
{
    __shared__ bf16_t T[64 * 66];
    const int bh = blockIdx.y, s0 = blockIdx.x * 64;
    const int tid = threadIdx.x;
    const size_t vb = (size_t)bh * SEQ * DHEAD;
#pragma unroll
    for (int h = 0; h < 2; ++h) {
        const int s = h * 32 + (tid >> 3), dc = (tid & 7) * 8;
        const bf16x8 vv = *(const bf16x8*)(v + vb + (size_t)(s0 + s) * DHEAD + dc);
#pragma unroll
        for (int j = 0; j < 8; ++j) T[(dc + j) * 66 + s] = vv[j];
    }
    __syncthreads();
    const size_t tb = (size_t)bh * DHEAD * SEQ;
    const uint32_t* Tw = (const uint32_t*)T;
#pragma unroll
    for (int h = 0; h < 2; ++h) {
        const int dh = h * 32 + (tid >> 3), kc = (tid & 7) * 8;
        uint4 o;
        o.x = Tw[dh * 33 + kc / 2 + 0];
        o.y = Tw[dh * 33 + kc / 2 + 1];
        o.z = Tw[dh * 33 + kc / 2 + 2];
        o.w = Tw[dh * 33 + kc / 2 + 3];
        // tiled dst: [kcg][dh][8], kcg = (s0+kc)/8
        *(uint4*)(vt + tb + (size_t)((s0 + kc) >> 3) * 512 + dh * 8) = o;
    }
}

// ---------------------------------------------------------------------------
// RMSNorm: fp32 row (1024) -> bf16 row
// ---------------------------------------------------------------------------
__global__ __launch_bounds__(256)
void rmsnorm_kernel(const float* __restrict__ x, const float* __restrict__ gw,
                    bf16_t* __restrict__ out)
{
    const int row = blockIdx.x, tid = threadIdx.x;
    const float4 v = ((const float4*)(x + (size_t)row * D_MODEL))[tid];
    float ss = v.x*v.x + v.y*v.y + v.z*v.z + v.w*v.w;
#pragma unroll
    for (int d = 1; d < 64; d <<= 1) ss += __shfl_xor(ss, d);
    __shared__ float red[4];
    if ((tid & 63) == 0) red[tid >> 6] = ss;
    __syncthreads();
    const float tot = red[0] + red[1] + red[2] + red[3];
    const float sc = rsqrtf(tot * (1.f / D_MODEL) + 1e-5f);
    const float4 gv = ((const float4*)gw)[tid];
    bf16x4 o;
    o[0] = (bf16_t)(v.x * sc * gv.x);
    o[1] = (bf16_t)(v.y * sc * gv.y);
    o[2] = (bf16_t)(v.z * sc * gv.z);
    o[3] = (bf16_t)(v.w * sc * gv.w);
    ((bf16x4*)(out + (size_t)row * D_MODEL))[tid] = o;
}

// ---------------------------------------------------------------------------
// 256x256 GEMM, coalesced staging + XOR-swizzled row-major LDS.
// (unchanged round-4 winner)
// ---------------------------------------------------------------------------
template <int MODE>
__global__ __launch_bounds__(512, 2)
void gemm256_kernel(const bf16_t* __restrict__ A, const bf16_t* __restrict__ Bt,
                    int M, int N, int K,
                    bf16_t* __restrict__ qo, bf16_t* __restrict__ ko, bf16_t* __restrict__ vo,
                    bf16_t* __restrict__ gate)
{
    __shared__ bf16x8 lds[8192];   // 128 KB
    const int tid  = threadIdx.x;
    const int wave = tid >> 6;
    const int lane = tid & 63;
    const int r = lane & 15, g = lane >> 4;
    const int wm = wave >> 2;
    const int wn = wave & 3;
    const int r3 = (r >> 3) & 1;
    const int gx = g ^ (((r >> 2) & 1) << 1);
    const int cx0 = r3 * 4 + gx;
    const int cx1 = cx0 ^ 4;

    int bx, by;
    xcd_swizzle(bx, by);
    const int row0 = by * 256;
    const int col0 = bx * 256;

    const f32x4 fzero = {0.f, 0.f, 0.f, 0.f};
    f32x4 acc[8][4];
#pragma unroll
    for (int i = 0; i < 8; ++i)
#pragma unroll
        for (int j = 0; j < 4; ++j) acc[i][j] = fzero;

    const int kcx = ((tid & 7) ^ (((tid >> 5) & 1) << 1) ^ (((tid >> 6) & 1) << 2)) * 8;
    const bf16_t* aSrc = A  + (size_t)(row0 + (tid >> 3)) * K + kcx;
    const bf16_t* bSrc = Bt + (size_t)(col0 + (tid >> 3)) * K + kcx;

    const int aRB = wm * 1024 + r * 8;
    const int bRB = 2048 + (wn >> 1) * 1024 + ((wn & 1) * 64 + r) * 8;

#define STA(nb, ktn, h_, j_) \
    async_ld16(&lds[(nb) + (h_) * 1024 + (j_) * 512 + tid], \
               aSrc + (size_t)((h_) * 128 + (j_) * 64) * K + (ktn))
#define STB(nb, ktn, h_, j_) \
    async_ld16(&lds[(nb) + 2048 + (h_) * 1024 + (j_) * 512 + tid], \
               bSrc + (size_t)((h_) * 128 + (j_) * 64) * K + (ktn))

    STB(0, 0, 0, 0); STB(0, 0, 0, 1); STB(0, 0, 1, 0); STB(0, 0, 1, 1);
    STA(0, 0, 0, 0); STA(0, 0, 1, 0);
    STA(0, 0, 0, 1); STA(0, 0, 1, 1);
    asm volatile("s_waitcnt vmcnt(2)" ::: "memory");
    __builtin_amdgcn_s_barrier();

    bf16x8 aF[8], bF[8];

    const int NT = K >> 6;
    for (int t = 0; t < NT; ++t) {
        const int AB  = (t & 1) << 12;
        const int nb  = AB ^ 4096;
        const int ktn = (t + 1) << 6;
        const bool pf = (t + 1) < NT;

        // ---- phase 0: quad (mh0, nh0) ----
#pragma unroll
        for (int q = 0; q < 4; ++q) {
            aF[q * 2 + 0] = lds[AB + aRB + q * 128 + cx0];
            aF[q * 2 + 1] = lds[AB + aRB + q * 128 + cx1];
        }
#pragma unroll
        for (int n = 0; n < 2; ++n) {
            bF[n * 2 + 0] = lds[AB + bRB + n * 128 + cx0];
            bF[n * 2 + 1] = lds[AB + bRB + n * 128 + cx1];
        }
        if (pf) { STB(nb, ktn, 0, 0); STB(nb, ktn, 0, 1); }
        __builtin_amdgcn_s_barrier();
        asm volatile("s_waitcnt lgkmcnt(0)" ::: "memory");
        __builtin_amdgcn_sched_barrier(0);
        __builtin_amdgcn_s_setprio(1);
#pragma unroll
        for (int q = 0; q < 4; ++q)
#pragma unroll
            for (int n = 0; n < 2; ++n)
#pragma unroll
                for (int ks = 0; ks < 2; ++ks)
                    acc[q][n] = __builtin_amdgcn_mfma_f32_16x16x32_bf16(
                        aF[q * 2 + ks], bF[n * 2 + ks], acc[q][n], 0, 0, 0);
        __builtin_amdgcn_s_setprio(0);
        __builtin_amdgcn_s_barrier();

        // ---- phase 1: quad (mh0, nh1) ----
#pragma unroll
        for (int n = 0; n < 2; ++n) {
            bF[4 + n * 2 + 0] = lds[AB + bRB + (32 + n * 16) * 8 + cx0];
            bF[4 + n * 2 + 1] = lds[AB + bRB + (32 + n * 16) * 8 + cx1];
        }
        if (pf) { STB(nb, ktn, 1, 0); STB(nb, ktn, 1, 1); }
        __builtin_amdgcn_s_barrier();
        asm volatile("s_waitcnt lgkmcnt(0)" ::: "memory");
        __builtin_amdgcn_sched_barrier(0);
        __builtin_amdgcn_s_setprio(1);
#pragma unroll
        for (int q = 0; q < 4; ++q)
#pragma unroll
            for (int n = 0; n < 2; ++n)
#pragma unroll
                for (int ks = 0; ks < 2; ++ks)
                    acc[q][2 + n] = __builtin_amdgcn_mfma_f32_16x16x32_bf16(
                        aF[q * 2 + ks], bF[4 + n * 2 + ks], acc[q][2 + n], 0, 0, 0);
        __builtin_amdgcn_s_setprio(0);
        if (pf) asm volatile("s_waitcnt vmcnt(4)" ::: "memory");
        else    asm volatile("s_waitcnt vmcnt(0)" ::: "memory");
        __builtin_amdgcn_s_barrier();

        // ---- phase 2: quad (mh1, nh1) ----
#pragma unroll
        for (int q = 0; q < 4; ++q) {
            aF[q * 2 + 0] = lds[AB + aRB + (64 + q * 16) * 8 + cx0];
            aF[q * 2 + 1] = lds[AB + aRB + (64 + q * 16) * 8 + cx1];
        }
        if (pf) { STA(nb, ktn, 0, 0); STA(nb, ktn, 1, 0); }
        __builtin_amdgcn_s_barrier();
        asm volatile("s_waitcnt lgkmcnt(0)" ::: "memory");
        __builtin_amdgcn_sched_barrier(0);
        __builtin_amdgcn_s_setprio(1);
#pragma unroll
        for (int q = 0; q < 4; ++q)
#pragma unroll
            for (int n = 0; n < 2; ++n)
#pragma unroll
                for (int ks = 0; ks < 2; ++ks)
                    acc[4 + q][2 + n] = __builtin_amdgcn_mfma_f32_16x16x32_bf16(
                        aF[q * 2 + ks], bF[4 + n * 2 + ks], acc[4 + q][2 + n], 0, 0, 0);
        __builtin_amdgcn_s_setprio(0);
        __builtin_amdgcn_s_barrier();

        // ---- phase 3: quad (mh1, nh0) ----
        if (pf) { STA(nb, ktn, 0, 1); STA(nb, ktn, 1, 1); }
        __builtin_amdgcn_s_barrier();
        __builtin_amdgcn_s_setprio(1);
#pragma unroll
        for (int q = 0; q < 4; ++q)
#pragma unroll
            for (int n = 0; n < 2; ++n)
#pragma unroll
                for (int ks = 0; ks < 2; ++ks)
                    acc[4 + q][n] = __builtin_amdgcn_mfma_f32_16x16x32_bf16(
                        aF[q * 2 + ks], bF[n * 2 + ks], acc[4 + q][n], 0, 0, 0);
        __builtin_amdgcn_s_setprio(0);
        if (pf) asm volatile("s_waitcnt vmcnt(2)" ::: "memory");
        __builtin_amdgcn_s_barrier();
    }
#undef STA
#undef STB

    const int mbase = row0 + wm * 128 + g * 4;
    const int nbase = col0 + wn * 64 + r;

    if constexpr (MODE == 2) {
#pragma unroll
        for (int np = 0; np < 2; ++np) {
            const int gc = (col0 >> 1) + wn * 32 + np * 16 + r;
#pragma unroll
            for (int mt = 0; mt < 8; ++mt) {
#pragma unroll
                for (int e = 0; e < 4; ++e) {
                    const float v1 = acc[mt][2 * np][e];
                    const float v3 = acc[mt][2 * np + 1][e];
                    const float sv = v1 * __builtin_amdgcn_rcpf(1.f + __expf(-v1));
                    const int grow = mbase + mt * 16 + e;
                    gate[(size_t)grow * DFF + gc] = (bf16_t)(sv * v3);
                }
            }
        }
    } else { // MODE 0
#pragma unroll
        for (int nt = 0; nt < 4; ++nt) {
            const int gcol = nbase + nt * 16;
            const int mat  = gcol >> 10;
            const int d    = gcol & 1023;
            const int head = d >> 6;
            const int dh   = d & 63;
            const float invf = __expf((float)(dh & ~1) * -0.14391157f);
            const size_t hb = (size_t)head * SEQ * DHEAD + dh;
#pragma unroll
            for (int mt = 0; mt < 8; ++mt) {
#pragma unroll
                for (int e = 0; e < 4; ++e) {
                    const float val = acc[mt][nt][e];
                    const float partner = __shfl_xor(val, 1);
                    const int grow = mbase + mt * 16 + e;
                    const int b = grow >> 11;
                    const int s = grow & 2047;
                    const size_t dst = (size_t)b * NHEADS * SEQ * DHEAD + hb + (size_t)s * DHEAD;
                    if (mat == 2) {
                        vo[dst] = (bf16_t)val;
                    } else {
                        float sn, cs;
                        __sincosf((float)s * invf, &sn, &cs);
                        const float rv = (dh & 1) ? (partner * sn + val * cs)
                                                  : (val * cs - partner * sn);
                        if (mat == 0) qo[dst] = (bf16_t)(rv * 0.125f);
                        else          ko[dst] = (bf16_t)rv;
                    }
                }
            }
        }
    }
}

// ---------------------------------------------------------------------------
// 128x128 GEMM (4 waves, 3 blocks/CU). (unchanged round-4 winner)
// ---------------------------------------------------------------------------
template <int MODE>
__global__ __launch_bounds__(256, 3)
void gemm128_kernel(const bf16_t* __restrict__ A, const bf16_t* __restrict__ Bt,
                    int M, int N, int K, const float* res, float* outf)
{
    __shared__ bf16x8 Al[1024];
    __shared__ bf16x8 Bl[1024];
    const int tid  = threadIdx.x;
    const int wave = tid >> 6;
    const int lane = tid & 63;
    const int r    = lane & 15;
    const int g    = lane >> 4;
    const int wm   = wave >> 1;
    const int wn   = wave & 1;
    const int r3 = (r >> 3) & 1;
    const int gx = g ^ (((r >> 2) & 1) << 1);
    const int cx0 = r3 * 4 + gx;
    const int cx1 = cx0 ^ 4;

    int bx, by;
    xcd_swizzle(bx, by);
    const int row0 = by * 128;
    const int col0 = bx * 128;

    const f32x4 fzero = {0.f, 0.f, 0.f, 0.f};
    f32x4 acc[4][4];
#pragma unroll
    for (int i = 0; i < 4; ++i)
#pragma unroll
        for (int j = 0; j < 4; ++j) acc[i][j] = fzero;

    const int kcx = ((tid & 7) ^ (((tid >> 5) & 1) << 1) ^ (((tid >> 6) & 1) << 2)) * 8;
    const bf16_t* a0 = A  + (size_t)(row0 + (tid >> 3)) * K + kcx;
    const bf16_t* b0 = Bt + (size_t)(col0 + (tid >> 3)) * K + kcx;

    for (int kt = 0; kt < K; kt += 64) {
#pragma unroll
        for (int j = 0; j < 4; ++j)
            async_ld16(&Al[j * 256 + tid], a0 + kt + (size_t)(j * 32) * K);
#pragma unroll
        for (int j = 0; j < 4; ++j)
            async_ld16(&Bl[j * 256 + tid], b0 + kt + (size_t)(j * 32) * K);
        __syncthreads();
#pragma unroll
        for (int s = 0; s < 2; ++s) {
            const int cx = s ? cx1 : cx0;
            bf16x8 af[4], bfr[4];
#pragma unroll
            for (int mt = 0; mt < 4; ++mt) af[mt]  = Al[(wm * 64 + mt * 16 + r) * 8 + cx];
#pragma unroll
            for (int nt = 0; nt < 4; ++nt) bfr[nt] = Bl[(wn * 64 + nt * 16 + r) * 8 + cx];
#pragma unroll
            for (int mt = 0; mt < 4; ++mt)
#pragma unroll
                for (int nt = 0; nt < 4; ++nt)
                    acc[mt][nt] = __builtin_amdgcn_mfma_f32_16x16x32_bf16(
                        af[mt], bfr[nt], acc[mt][nt], 0, 0, 0);
        }
        __syncthreads();
    }

    const int mbase = row0 + wm * 64 + g * 4;
    const int nbase = col0 + wn * 64 + r;
#pragma unroll
    for (int mt = 0; mt < 4; ++mt) {
#pragma unroll
        for (int nt = 0; nt < 4; ++nt) {
#pragma unroll
            for (int e = 0; e < 4; ++e) {
                const int grow = mbase + mt * 16 + e;
                const int gcol = nbase + nt * 16;
                const size_t idx = (size_t)grow * D_MODEL + gcol;
                outf[idx] = res[idx] + acc[mt][nt][e];
            }
        }
    }
}

// ---------------------------------------------------------------------------
// Causal flash attention. q(pre-scaled)/k: [B,H,S,Dh]; vT tiled [kc][dh][8].
// KVBLK=64. LDS 48KB: K dbuf 2x8K + V dbuf 2x8K + P 16K -> 3 blocks/CU.
// Double-buffered staging w/ counted vmcnt(4) (never drain-0 mid-loop).
// li row-sum via MFMA(P, ones) -> no shfl sum reduce. Defer-max (THR=8)
// skips alpha-rescale on a wave-uniform __all check.
// ---------------------------------------------------------------------------
__global__ __launch_bounds__(256, 3)
void attn_kernel(const bf16_t* __restrict__ qg, const bf16_t* __restrict__ kg,
                 const bf16_t* __restrict__ vT, bf16_t* __restrict__ ctx)
{
    __shared__ bf16x8 lds[3072];   // K0 K1 V0 V1 P : 512 each, P 1024
    const int qblk = (gridDim.x - 1) - blockIdx.x;
    const int bh   = blockIdx.y;
    const int tid  = threadIdx.x;
    const int wave = tid >> 6;
    const int lane = tid & 63;
    const int r = lane & 15, g = lane >> 4;
    const size_t base = (size_t)bh * SEQ * DHEAD;
    const int qw = qblk * 128 + wave * 32;

    bf16x8 qf[2][2];
#pragma unroll
    for (int rt = 0; rt < 2; ++rt)
#pragma unroll
        for (int kh = 0; kh < 2; ++kh)
            qf[rt][kh] = *(const bf16x8*)(qg + base + (size_t)(qw + rt*16 + r) * DHEAD + kh*32 + g*8);

    const f32x4 fzero = {0.f, 0.f, 0.f, 0.f};
    bf16x8 onesf;
#pragma unroll
    for (int j = 0; j < 8; ++j) onesf[j] = (bf16_t)1.f;

    f32x4 O[2][4];
    float mi[2][4], li[2][4];
#pragma unroll
    for (int rt = 0; rt < 2; ++rt)
#pragma unroll
        for (int e = 0; e < 4; ++e) { mi[rt][e] = -1e30f; li[rt][e] = 0.f; }
#pragma unroll
    for (int rt = 0; rt < 2; ++rt)
#pragma unroll
        for (int d = 0; d < 4; ++d) O[rt][d] = fzero;

    bf16_t* const Pb = (bf16_t*)&lds[2048 + wave * 256];  // 32 qrows x 64 keys
    const int pcx = ((r >> 2) & 3) << 1;                   // read-side chunk XOR

    // staging: K[buf] at buf*512, V[buf] at 1024 + buf*512; 4 loads/wave/tile
#define STAGEKV(k0_, B_) { \
        const bf16_t* kp_ = kg + base + (size_t)((k0_) + lane) * DHEAD + wave * 8; \
        async_ld16(&lds[(B_) * 512 + tid], kp_); \
        async_ld16(&lds[(B_) * 512 + 256 + tid], kp_ + 32); \
        const bf16_t* vp_ = vT + base + (size_t)(k0_) * DHEAD + tid * 8; \
        async_ld16(&lds[1024 + (B_) * 512 + tid], vp_); \
        async_ld16(&lds[1024 + (B_) * 512 + 256 + tid], vp_ + 2048); }

    const int NKB = 2 * qblk + 2;
    STAGEKV(0, 0);
    for (int kb = 0; kb < NKB; ++kb) {
        const int k0 = kb * 64;
        const bool pf = (kb + 1) < NKB;
        if (pf) STAGEKV((kb + 1) * 64, (kb + 1) & 1);
        if (pf) asm volatile("s_waitcnt vmcnt(4)" ::: "memory");
        else    asm volatile("s_waitcnt vmcnt(0)" ::: "memory");
        __syncthreads();

        if (k0 <= qw + 31) {   // wave-uniform: tile has >=1 unmasked key
            const int KB = (kb & 1) * 512;
            const int VB = 1024 + (kb & 1) * 512;
            f32x4 sc[2][4];
            __builtin_amdgcn_s_setprio(1);
#pragma unroll
            for (int ct = 0; ct < 4; ++ct) {
                const bf16x8 kf0 = lds[KB + g * 64 + ct * 16 + r];
                const bf16x8 kf1 = lds[KB + 256 + g * 64 + ct * 16 + r];
                sc[0][ct] = __builtin_amdgcn_mfma_f32_16x16x32_bf16(qf[0][0], kf0, fzero, 0, 0, 0);
                sc[0][ct] = __builtin_amdgcn_mfma_f32_16x16x32_bf16(qf[0][1], kf1, sc[0][ct], 0, 0, 0);
                sc[1][ct] = __builtin_amdgcn_mfma_f32_16x16x32_bf16(qf[1][0], kf0, fzero, 0, 0, 0);
                sc[1][ct] = __builtin_amdgcn_mfma_f32_16x16x32_bf16(qf[1][1], kf1, sc[1][ct], 0, 0, 0);
            }
            __builtin_amdgcn_s_setprio(0);
            if (k0 + 63 > qw) { // near-diagonal: causal mask
#pragma unroll
                for (int rt = 0; rt < 2; ++rt)
#pragma unroll
                    for (int ct = 0; ct < 4; ++ct)
#pragma unroll
                        for (int e = 0; e < 4; ++e)
                            if (k0 + ct * 16 + r > qw + rt * 16 + g * 4 + e)
                                sc[rt][ct][e] = -1e30f;
            }
            // row maxes (in-reg + 4-level shfl over r)
            float mx[2][4];
#pragma unroll
            for (int rt = 0; rt < 2; ++rt)
#pragma unroll
                for (int e = 0; e < 4; ++e) {
                    float m = fmaxf(fmaxf(sc[rt][0][e], sc[rt][1][e]),
                                    fmaxf(sc[rt][2][e], sc[rt][3][e]));
#pragma unroll
                    for (int d = 1; d < 16; d <<= 1) m = fmaxf(m, __shfl_xor(m, d));
                    mx[rt][e] = m;
                }
            // defer-max: one wave-uniform decision for all 8 rows
            float worst = mx[0][0] - mi[0][0];
#pragma unroll
            for (int rt = 0; rt < 2; ++rt)
#pragma unroll
                for (int e = 0; e < 4; ++e)
                    worst = fmaxf(worst, mx[rt][e] - mi[rt][e]);
            if (!__all(worst <= 8.f)) {
#pragma unroll
                for (int rt = 0; rt < 2; ++rt)
#pragma unroll
                    for (int e = 0; e < 4; ++e) {
                        const float mnew  = fmaxf(mi[rt][e], mx[rt][e]);
                        const float alpha = __expf(mi[rt][e] - mnew);
                        mi[rt][e] = mnew;
                        li[rt][e] *= alpha;
#pragma unroll
                        for (int dht = 0; dht < 4; ++dht) O[rt][dht][e] *= alpha;
                    }
            }
            // P = exp(sc - mi) -> LDS (bf16), banks 2-way (free)
#pragma unroll
            for (int rt = 0; rt < 2; ++rt)
#pragma unroll
                for (int e = 0; e < 4; ++e) {
                    const int qlocal = rt * 16 + g * 4 + e;
#pragma unroll
                    for (int ct = 0; ct < 4; ++ct)
                        Pb[qlocal * 64 + ((ct * 16 + r) ^ (g << 4))] =
                            (bf16_t)__expf(sc[rt][ct][e] - mi[rt][e]);
                }
            // PV + row-sum via MFMA(P, ones)
            f32x4 S[2] = {fzero, fzero};
            __builtin_amdgcn_s_setprio(1);
#pragma unroll
            for (int kt = 0; kt < 2; ++kt) {
                const int cix = (kt * 4 + g) ^ pcx;
                const bf16x8 pf0 = lds[2048 + wave * 256 + r * 8 + cix];
                const bf16x8 pf1 = lds[2048 + wave * 256 + 128 + r * 8 + cix];
#pragma unroll
                for (int dht = 0; dht < 4; ++dht) {
                    const bf16x8 vf = lds[VB + (kt * 4 + g) * 64 + dht * 16 + r];
                    O[0][dht] = __builtin_amdgcn_mfma_f32_16x16x32_bf16(pf0, vf, O[0][dht], 0, 0, 0);
                    O[1][dht] = __builtin_amdgcn_mfma_f32_16x16x32_bf16(pf1, vf, O[1][dht], 0, 0, 0);
                }
                S[0] = __builtin_amdgcn_mfma_f32_16x16x32_bf16(pf0, onesf, S[0], 0, 0, 0);
                S[1] = __builtin_amdgcn_mfma_f32_16x16x32_bf16(pf1, onesf, S[1], 0, 0, 0);
            }
            __builtin_amdgcn_s_setprio(0);
#pragma unroll
            for (int rt = 0; rt < 2; ++rt)
#pragma unroll
                for (int e = 0; e < 4; ++e) li[rt][e] += S[rt][e];
        }
        __syncthreads();
    }
#undef STAGEKV

    const int b = bh >> 4, head = bh & 15;
#pragma unroll
    for (int rt = 0; rt < 2; ++rt) {
#pragma unroll
        for (int e = 0; e < 4; ++e) {
            const float inv = __builtin_amdgcn_rcpf(li[rt][e]);
            const int s = qw + rt * 16 + g * 4 + e;
            bf16_t* op = ctx + ((size_t)(b * SEQ + s)) * D_MODEL + head * DHEAD + r;
#pragma unroll
            for (int dht = 0; dht < 4; ++dht)
                op[dht * 16] = (bf16_t)(O[rt][dht][e] * inv);
        }
    }
}

// ---------------------------------------------------------------------------
extern "C" void kernel_launch(void* const* d_in, const int* in_sizes, int n_in,
                              void* d_out, int out_size, void* d_ws, size_t ws_size,
                              hipStream_t stream)
{
    (void)in_sizes; (void)n_in; (void)out_size; (void)ws_size;
    const float* x  = (const float*)d_in[0];
    const float* g1 = (const float*)d_in[2];
    const float* g2 = (const float*)d_in[3];
    const float* wq = (const float*)d_in[4];
    const float* wk = (const float*)d_in[5];
    const float* wv = (const float*)d_in[6];
    const float* wo = (const float*)d_in[7];
    const float* w1 = (const float*)d_in[8];
    const float* w2 = (const float*)d_in[9];
    const float* w3 = (const float*)d_in[10];
    float* out = (float*)d_out;
    char* ws = (char*)d_ws;
    const size_t MB = 1ull << 20;
    bf16_t* wqkvT = (bf16_t*)(ws + 0);        // 3072 x 1024
    bf16_t* woT   = (bf16_t*)(ws + 6  * MB);  // 1024 x 1024
    bf16_t* w13T  = (bf16_t*)(ws + 8  * MB);  // 8192 x 1024 (16-col-group ilv)
    bf16_t* w2T   = (bf16_t*)(ws + 24 * MB);  // 1024 x 4096
    bf16_t* hbuf  = (bf16_t*)(ws + 32 * MB);  // h / h2; reused as vT during attn
    bf16_t* qbuf  = (bf16_t*)(ws + 48 * MB);
    bf16_t* kbuf  = (bf16_t*)(ws + 64 * MB);
    bf16_t* vbuf  = (bf16_t*)(ws + 80 * MB);
    bf16_t* ctx   = (bf16_t*)(ws + 96 * MB);
    bf16_t* gate  = (bf16_t*)(ws + 48 * MB);  // 8192 x 4096, reuses q/k/v/ctx
    bf16_t* vTb   = hbuf;                     // tiled [bh][kc][dh][8]

    dim3 blk(256);
    dim3 blk5(512);
    transpose_cast_kernel<<<dim3(32, 32),  blk, 0, stream>>>(wq, wqkvT,             1024, 1024, 16, 0);
    transpose_cast_kernel<<<dim3(32, 32),  blk, 0, stream>>>(wk, wqkvT + 1024*1024, 1024, 1024, 16, 0);
    transpose_cast_kernel<<<dim3(32, 32),  blk, 0, stream>>>(wv, wqkvT + 2048*1024, 1024, 1024, 16, 0);
    transpose_cast_kernel<<<dim3(32, 32),  blk, 0, stream>>>(wo, woT,               1024, 1024, 16, 0);
    transpose_cast_kernel<<<dim3(128, 32), blk, 0, stream>>>(w1, w13T,              1024, 4096, 32, 0);
    transpose_cast_kernel<<<dim3(128, 32), blk, 0, stream>>>(w3, w13T,              1024, 4096, 32, 16);
    transpose_cast_kernel<<<dim3(32, 128), blk, 0, stream>>>(w2, w2T,               4096, 1024, 16, 0);

    rmsnorm_kernel<<<dim3(8192), blk, 0, stream>>>(x, g1, hbuf);

    gemm256_kernel<0><<<dim3(12, 32), blk5, 0, stream>>>(hbuf, wqkvT, 8192, 3072, 1024,
        qbuf, kbuf, vbuf, nullptr);

    transpose_v_kernel<<<dim3(32, 64), blk, 0, stream>>>(vbuf, vTb);

    attn_kernel<<<dim3(16, 64), blk, 0, stream>>>(qbuf, kbuf, vTb, ctx);

    gemm128_kernel<1><<<dim3(8, 64), blk, 0, stream>>>(ctx, woT, 8192, 1024, 1024, x, out);

    rmsnorm_kernel<<<dim3(8192), blk, 0, stream>>>(out, g2, hbuf);

    gemm256_kernel<2><<<dim3(32, 32), blk5, 0, stream>>>(hbuf, w13T, 8192, 8192, 1024,
        nullptr, nullptr, nullptr, gate);

    gemm128_kernel<3><<<dim3(8, 64), blk, 0, stream>>>(gate, w2T, 8192, 1024, 4096, out, out);
}

// Round 7
// 598.862 us; speedup vs baseline: 1.1676x; 1.1331x over previous
//
#include <hip/hip_runtime.h>
#include <hip/hip_bf16.h>
#include <cstdint>
#include <cstddef>

typedef __bf16 bf16_t;
typedef __bf16 bf16x8 __attribute__((ext_vector_type(8)));
typedef __bf16 bf16x4 __attribute__((ext_vector_type(4)));
typedef float  f32x4  __attribute__((ext_vector_type(4)));

#define D_MODEL 1024
#define SEQ     2048
#define NHEADS  16
#define DHEAD   64
#define DFF     4096

// async global->LDS, 16B per lane; lds base must be wave-uniform (dest = base + lane*16)
__device__ __forceinline__ void async_ld16(void* lds, const void* g) {
    __builtin_amdgcn_global_load_lds(
        (__attribute__((address_space(1))) void*)(void*)(g),
        (__attribute__((address_space(3))) void*)(lds), 16, 0, 0);
}

// Resident-operand XCD swizzle: XCD x owns by-chunk [x*cy, (x+1)*cy) which
// stays L2-resident; bx sweeps. Requires gridDim.y % 8 == 0 (bijective).
__device__ __forceinline__ void xcd_swizzle(int& bx, int& by) {
    const int gy = gridDim.y;
    const int i = blockIdx.x + gridDim.x * blockIdx.y;
    if ((gy & 7) == 0) {
        const int cy = gy >> 3;
        const int xcd = i & 7, j = i >> 3;
        bx = j / cy;
        by = xcd * cy + (j % cy);
    } else { bx = blockIdx.x; by = blockIdx.y; }
}

// ---------------------------------------------------------------------------
// fp32 (K x N) -> bf16 transposed; dst row for source col n:
//   (n>>4)*gstride + (n&15) + goff
// ---------------------------------------------------------------------------
__global__ __launch_bounds__(256)
void transpose_cast_kernel(const float* __restrict__ src, bf16_t* __restrict__ dst,
                           int K, int N, int gstride, int goff)
{
    __shared__ float tile[32][33];
    const int bn = blockIdx.x * 32, bk = blockIdx.y * 32;
    const int tx = threadIdx.x & 31, ty = threadIdx.x >> 5;
#pragma unroll
    for (int i = 0; i < 32; i += 8)
        tile[ty + i][tx] = src[(size_t)(bk + ty + i) * N + bn + tx];
    __syncthreads();
#pragma unroll
    for (int i = 0; i < 32; i += 8) {
        const int n = bn + ty + i, kk = bk + tx;
        const int row = (n >> 4) * gstride + (n & 15) + goff;
        dst[(size_t)row * K + kk] = (bf16_t)tile[tx][ty + i];
    }
}

// ---------------------------------------------------------------------------
// bf16 V [bh][s][dh] -> vT tiled [bh][kc=s/8][dh][8] (so attn V-staging is a
// LINEAR global_load_lds stream).
// ---------------------------------------------------------------------------
__global__ __launch_bounds__(256)
void transpose_v_kernel(const bf16_t* __restrict__ v, bf16_t* __restrict__ vt)
{
    __shared__ bf16_t T[64 * 66];
    const int bh = blockIdx.y, s0 = blockIdx.x * 64;
    const int tid = threadIdx.x;
    const size_t vb = (size_t)bh * SEQ * DHEAD;
#pragma unroll
    for (int h = 0; h < 2; ++h) {
        const int s = h * 32 + (tid >> 3), dc = (tid & 7) * 8;
        const bf16x8 vv = *(const bf16x8*)(v + vb + (size_t)(s0 + s) * DHEAD + dc);
#pragma unroll
        for (int j = 0; j < 8; ++j) T[(dc + j) * 66 + s] = vv[j];
    }
    __syncthreads();
    const size_t tb = (size_t)bh * DHEAD * SEQ;
    const uint32_t* Tw = (const uint32_t*)T;
#pragma unroll
    for (int h = 0; h < 2; ++h) {
        const int dh = h * 32 + (tid >> 3), kc = (tid & 7) * 8;
        uint4 o;
        o.x = Tw[dh * 33 + kc / 2 + 0];
        o.y = Tw[dh * 33 + kc / 2 + 1];
        o.z = Tw[dh * 33 + kc / 2 + 2];
        o.w = Tw[dh * 33 + kc / 2 + 3];
        // tiled dst: [kcg][dh][8], kcg = (s0+kc)/8
        *(uint4*)(vt + tb + (size_t)((s0 + kc) >> 3) * 512 + dh * 8) = o;
    }
}

// ---------------------------------------------------------------------------
// RMSNorm: fp32 row (1024) -> bf16 row
// ---------------------------------------------------------------------------
__global__ __launch_bounds__(256)
void rmsnorm_kernel(const float* __restrict__ x, const float* __restrict__ gw,
                    bf16_t* __restrict__ out)
{
    const int row = blockIdx.x, tid = threadIdx.x;
    const float4 v = ((const float4*)(x + (size_t)row * D_MODEL))[tid];
    float ss = v.x*v.x + v.y*v.y + v.z*v.z + v.w*v.w;
#pragma unroll
    for (int d = 1; d < 64; d <<= 1) ss += __shfl_xor(ss, d);
    __shared__ float red[4];
    if ((tid & 63) == 0) red[tid >> 6] = ss;
    __syncthreads();
    const float tot = red[0] + red[1] + red[2] + red[3];
    const float sc = rsqrtf(tot * (1.f / D_MODEL) + 1e-5f);
    const float4 gv = ((const float4*)gw)[tid];
    bf16x4 o;
    o[0] = (bf16_t)(v.x * sc * gv.x);
    o[1] = (bf16_t)(v.y * sc * gv.y);
    o[2] = (bf16_t)(v.z * sc * gv.z);
    o[3] = (bf16_t)(v.w * sc * gv.w);
    ((bf16x4*)(out + (size_t)row * D_MODEL))[tid] = o;
}

// ---------------------------------------------------------------------------
// 256x256 GEMM, coalesced staging + XOR-swizzled row-major LDS.
// (unchanged round-4 winner)
// ---------------------------------------------------------------------------
template <int MODE>
__global__ __launch_bounds__(512, 2)
void gemm256_kernel(const bf16_t* __restrict__ A, const bf16_t* __restrict__ Bt,
                    int M, int N, int K,
                    bf16_t* __restrict__ qo, bf16_t* __restrict__ ko, bf16_t* __restrict__ vo,
                    bf16_t* __restrict__ gate)
{
    __shared__ bf16x8 lds[8192];   // 128 KB
    const int tid  = threadIdx.x;
    const int wave = tid >> 6;
    const int lane = tid & 63;
    const int r = lane & 15, g = lane >> 4;
    const int wm = wave >> 2;
    const int wn = wave & 3;
    const int r3 = (r >> 3) & 1;
    const int gx = g ^ (((r >> 2) & 1) << 1);
    const int cx0 = r3 * 4 + gx;
    const int cx1 = cx0 ^ 4;

    int bx, by;
    xcd_swizzle(bx, by);
    const int row0 = by * 256;
    const int col0 = bx * 256;

    const f32x4 fzero = {0.f, 0.f, 0.f, 0.f};
    f32x4 acc[8][4];
#pragma unroll
    for (int i = 0; i < 8; ++i)
#pragma unroll
        for (int j = 0; j < 4; ++j) acc[i][j] = fzero;

    const int kcx = ((tid & 7) ^ (((tid >> 5) & 1) << 1) ^ (((tid >> 6) & 1) << 2)) * 8;
    const bf16_t* aSrc = A  + (size_t)(row0 + (tid >> 3)) * K + kcx;
    const bf16_t* bSrc = Bt + (size_t)(col0 + (tid >> 3)) * K + kcx;

    const int aRB = wm * 1024 + r * 8;
    const int bRB = 2048 + (wn >> 1) * 1024 + ((wn & 1) * 64 + r) * 8;

#define STA(nb, ktn, h_, j_) \
    async_ld16(&lds[(nb) + (h_) * 1024 + (j_) * 512 + tid], \
               aSrc + (size_t)((h_) * 128 + (j_) * 64) * K + (ktn))
#define STB(nb, ktn, h_, j_) \
    async_ld16(&lds[(nb) + 2048 + (h_) * 1024 + (j_) * 512 + tid], \
               bSrc + (size_t)((h_) * 128 + (j_) * 64) * K + (ktn))

    STB(0, 0, 0, 0); STB(0, 0, 0, 1); STB(0, 0, 1, 0); STB(0, 0, 1, 1);
    STA(0, 0, 0, 0); STA(0, 0, 1, 0);
    STA(0, 0, 0, 1); STA(0, 0, 1, 1);
    asm volatile("s_waitcnt vmcnt(2)" ::: "memory");
    __builtin_amdgcn_s_barrier();

    bf16x8 aF[8], bF[8];

    const int NT = K >> 6;
    for (int t = 0; t < NT; ++t) {
        const int AB  = (t & 1) << 12;
        const int nb  = AB ^ 4096;
        const int ktn = (t + 1) << 6;
        const bool pf = (t + 1) < NT;

        // ---- phase 0: quad (mh0, nh0) ----
#pragma unroll
        for (int q = 0; q < 4; ++q) {
            aF[q * 2 + 0] = lds[AB + aRB + q * 128 + cx0];
            aF[q * 2 + 1] = lds[AB + aRB + q * 128 + cx1];
        }
#pragma unroll
        for (int n = 0; n < 2; ++n) {
            bF[n * 2 + 0] = lds[AB + bRB + n * 128 + cx0];
            bF[n * 2 + 1] = lds[AB + bRB + n * 128 + cx1];
        }
        if (pf) { STB(nb, ktn, 0, 0); STB(nb, ktn, 0, 1); }
        __builtin_amdgcn_s_barrier();
        asm volatile("s_waitcnt lgkmcnt(0)" ::: "memory");
        __builtin_amdgcn_sched_barrier(0);
        __builtin_amdgcn_s_setprio(1);
#pragma unroll
        for (int q = 0; q < 4; ++q)
#pragma unroll
            for (int n = 0; n < 2; ++n)
#pragma unroll
                for (int ks = 0; ks < 2; ++ks)
                    acc[q][n] = __builtin_amdgcn_mfma_f32_16x16x32_bf16(
                        aF[q * 2 + ks], bF[n * 2 + ks], acc[q][n], 0, 0, 0);
        __builtin_amdgcn_s_setprio(0);
        __builtin_amdgcn_s_barrier();

        // ---- phase 1: quad (mh0, nh1) ----
#pragma unroll
        for (int n = 0; n < 2; ++n) {
            bF[4 + n * 2 + 0] = lds[AB + bRB + (32 + n * 16) * 8 + cx0];
            bF[4 + n * 2 + 1] = lds[AB + bRB + (32 + n * 16) * 8 + cx1];
        }
        if (pf) { STB(nb, ktn, 1, 0); STB(nb, ktn, 1, 1); }
        __builtin_amdgcn_s_barrier();
        asm volatile("s_waitcnt lgkmcnt(0)" ::: "memory");
        __builtin_amdgcn_sched_barrier(0);
        __builtin_amdgcn_s_setprio(1);
#pragma unroll
        for (int q = 0; q < 4; ++q)
#pragma unroll
            for (int n = 0; n < 2; ++n)
#pragma unroll
                for (int ks = 0; ks < 2; ++ks)
                    acc[q][2 + n] = __builtin_amdgcn_mfma_f32_16x16x32_bf16(
                        aF[q * 2 + ks], bF[4 + n * 2 + ks], acc[q][2 + n], 0, 0, 0);
        __builtin_amdgcn_s_setprio(0);
        if (pf) asm volatile("s_waitcnt vmcnt(4)" ::: "memory");
        else    asm volatile("s_waitcnt vmcnt(0)" ::: "memory");
        __builtin_amdgcn_s_barrier();

        // ---- phase 2: quad (mh1, nh1) ----
#pragma unroll
        for (int q = 0; q < 4; ++q) {
            aF[q * 2 + 0] = lds[AB + aRB + (64 + q * 16) * 8 + cx0];
            aF[q * 2 + 1] = lds[AB + aRB + (64 + q * 16) * 8 + cx1];
        }
        if (pf) { STA(nb, ktn, 0, 0); STA(nb, ktn, 1, 0); }
        __builtin_amdgcn_s_barrier();
        asm volatile("s_waitcnt lgkmcnt(0)" ::: "memory");
        __builtin_amdgcn_sched_barrier(0);
        __builtin_amdgcn_s_setprio(1);
#pragma unroll
        for (int q = 0; q < 4; ++q)
#pragma unroll
            for (int n = 0; n < 2; ++n)
#pragma unroll
                for (int ks = 0; ks < 2; ++ks)
                    acc[4 + q][2 + n] = __builtin_amdgcn_mfma_f32_16x16x32_bf16(
                        aF[q * 2 + ks], bF[4 + n * 2 + ks], acc[4 + q][2 + n], 0, 0, 0);
        __builtin_amdgcn_s_setprio(0);
        __builtin_amdgcn_s_barrier();

        // ---- phase 3: quad (mh1, nh0) ----
        if (pf) { STA(nb, ktn, 0, 1); STA(nb, ktn, 1, 1); }
        __builtin_amdgcn_s_barrier();
        __builtin_amdgcn_s_setprio(1);
#pragma unroll
        for (int q = 0; q < 4; ++q)
#pragma unroll
            for (int n = 0; n < 2; ++n)
#pragma unroll
                for (int ks = 0; ks < 2; ++ks)
                    acc[4 + q][n] = __builtin_amdgcn_mfma_f32_16x16x32_bf16(
                        aF[q * 2 + ks], bF[n * 2 + ks], acc[4 + q][n], 0, 0, 0);
        __builtin_amdgcn_s_setprio(0);
        if (pf) asm volatile("s_waitcnt vmcnt(2)" ::: "memory");
        __builtin_amdgcn_s_barrier();
    }
#undef STA
#undef STB

    const int mbase = row0 + wm * 128 + g * 4;
    const int nbase = col0 + wn * 64 + r;

    if constexpr (MODE == 2) {
#pragma unroll
        for (int np = 0; np < 2; ++np) {
            const int gc = (col0 >> 1) + wn * 32 + np * 16 + r;
#pragma unroll
            for (int mt = 0; mt < 8; ++mt) {
#pragma unroll
                for (int e = 0; e < 4; ++e) {
                    const float v1 = acc[mt][2 * np][e];
                    const float v3 = acc[mt][2 * np + 1][e];
                    const float sv = v1 * __builtin_amdgcn_rcpf(1.f + __expf(-v1));
                    const int grow = mbase + mt * 16 + e;
                    gate[(size_t)grow * DFF + gc] = (bf16_t)(sv * v3);
                }
            }
        }
    } else { // MODE 0
#pragma unroll
        for (int nt = 0; nt < 4; ++nt) {
            const int gcol = nbase + nt * 16;
            const int mat  = gcol >> 10;
            const int d    = gcol & 1023;
            const int head = d >> 6;
            const int dh   = d & 63;
            const float invf = __expf((float)(dh & ~1) * -0.14391157f);
            const size_t hb = (size_t)head * SEQ * DHEAD + dh;
#pragma unroll
            for (int mt = 0; mt < 8; ++mt) {
#pragma unroll
                for (int e = 0; e < 4; ++e) {
                    const float val = acc[mt][nt][e];
                    const float partner = __shfl_xor(val, 1);
                    const int grow = mbase + mt * 16 + e;
                    const int b = grow >> 11;
                    const int s = grow & 2047;
                    const size_t dst = (size_t)b * NHEADS * SEQ * DHEAD + hb + (size_t)s * DHEAD;
                    if (mat == 2) {
                        vo[dst] = (bf16_t)val;
                    } else {
                        float sn, cs;
                        __sincosf((float)s * invf, &sn, &cs);
                        const float rv = (dh & 1) ? (partner * sn + val * cs)
                                                  : (val * cs - partner * sn);
                        if (mat == 0) qo[dst] = (bf16_t)(rv * 0.125f);
                        else          ko[dst] = (bf16_t)rv;
                    }
                }
            }
        }
    }
}

// ---------------------------------------------------------------------------
// 128x128 GEMM (4 waves, 3 blocks/CU). (unchanged round-4 winner)
// ---------------------------------------------------------------------------
template <int MODE>
__global__ __launch_bounds__(256, 3)
void gemm128_kernel(const bf16_t* __restrict__ A, const bf16_t* __restrict__ Bt,
                    int M, int N, int K, const float* res, float* outf)
{
    __shared__ bf16x8 Al[1024];
    __shared__ bf16x8 Bl[1024];
    const int tid  = threadIdx.x;
    const int wave = tid >> 6;
    const int lane = tid & 63;
    const int r    = lane & 15;
    const int g    = lane >> 4;
    const int wm   = wave >> 1;
    const int wn   = wave & 1;
    const int r3 = (r >> 3) & 1;
    const int gx = g ^ (((r >> 2) & 1) << 1);
    const int cx0 = r3 * 4 + gx;
    const int cx1 = cx0 ^ 4;

    int bx, by;
    xcd_swizzle(bx, by);
    const int row0 = by * 128;
    const int col0 = bx * 128;

    const f32x4 fzero = {0.f, 0.f, 0.f, 0.f};
    f32x4 acc[4][4];
#pragma unroll
    for (int i = 0; i < 4; ++i)
#pragma unroll
        for (int j = 0; j < 4; ++j) acc[i][j] = fzero;

    const int kcx = ((tid & 7) ^ (((tid >> 5) & 1) << 1) ^ (((tid >> 6) & 1) << 2)) * 8;
    const bf16_t* a0 = A  + (size_t)(row0 + (tid >> 3)) * K + kcx;
    const bf16_t* b0 = Bt + (size_t)(col0 + (tid >> 3)) * K + kcx;

    for (int kt = 0; kt < K; kt += 64) {
#pragma unroll
        for (int j = 0; j < 4; ++j)
            async_ld16(&Al[j * 256 + tid], a0 + kt + (size_t)(j * 32) * K);
#pragma unroll
        for (int j = 0; j < 4; ++j)
            async_ld16(&Bl[j * 256 + tid], b0 + kt + (size_t)(j * 32) * K);
        __syncthreads();
#pragma unroll
        for (int s = 0; s < 2; ++s) {
            const int cx = s ? cx1 : cx0;
            bf16x8 af[4], bfr[4];
#pragma unroll
            for (int mt = 0; mt < 4; ++mt) af[mt]  = Al[(wm * 64 + mt * 16 + r) * 8 + cx];
#pragma unroll
            for (int nt = 0; nt < 4; ++nt) bfr[nt] = Bl[(wn * 64 + nt * 16 + r) * 8 + cx];
#pragma unroll
            for (int mt = 0; mt < 4; ++mt)
#pragma unroll
                for (int nt = 0; nt < 4; ++nt)
                    acc[mt][nt] = __builtin_amdgcn_mfma_f32_16x16x32_bf16(
                        af[mt], bfr[nt], acc[mt][nt], 0, 0, 0);
        }
        __syncthreads();
    }

    const int mbase = row0 + wm * 64 + g * 4;
    const int nbase = col0 + wn * 64 + r;
#pragma unroll
    for (int mt = 0; mt < 4; ++mt) {
#pragma unroll
        for (int nt = 0; nt < 4; ++nt) {
#pragma unroll
            for (int e = 0; e < 4; ++e) {
                const int grow = mbase + mt * 16 + e;
                const int gcol = nbase + nt * 16;
                const size_t idx = (size_t)grow * D_MODEL + gcol;
                outf[idx] = res[idx] + acc[mt][nt][e];
            }
        }
    }
}

// ---------------------------------------------------------------------------
// Causal flash attention. q(pre-scaled)/k: [B,H,S,Dh]; vT tiled [kc][dh][8].
// KVBLK=64. LDS 48KB (K dbuf + V dbuf + P) -> 3 blocks/CU.
// Heavy-first 1D grid: qblk = 15 - (bx>>6), bh = bx&63 -> all heavy blocks
// dispatch first (kills the tail; also pins each bh's K/V to one XCD's L2).
// K LDS layout [key][chunk^key&7] (XOR both sides): staging is 8-lane/row
// coalesced AND QK reads are conflict-free.
// Double-buffered staging w/ counted vmcnt(4); li row-sum via MFMA(P,ones);
// defer-max (THR=8).
// ---------------------------------------------------------------------------
__global__ __launch_bounds__(256, 3)
void attn_kernel(const bf16_t* __restrict__ qg, const bf16_t* __restrict__ kg,
                 const bf16_t* __restrict__ vT, bf16_t* __restrict__ ctx)
{
    __shared__ bf16x8 lds[3072];   // K0 K1 V0 V1 : 512 each, P 1024
    const int qblk = 15 - (blockIdx.x >> 6);
    const int bh   = blockIdx.x & 63;
    const int tid  = threadIdx.x;
    const int wave = tid >> 6;
    const int lane = tid & 63;
    const int r = lane & 15, g = lane >> 4;
    const size_t base = (size_t)bh * SEQ * DHEAD;
    const int qw = qblk * 128 + wave * 32;

    bf16x8 qf[2][2];
#pragma unroll
    for (int rt = 0; rt < 2; ++rt)
#pragma unroll
        for (int kh = 0; kh < 2; ++kh)
            qf[rt][kh] = *(const bf16x8*)(qg + base + (size_t)(qw + rt*16 + r) * DHEAD + kh*32 + g*8);

    const f32x4 fzero = {0.f, 0.f, 0.f, 0.f};
    bf16x8 onesf;
#pragma unroll
    for (int j = 0; j < 8; ++j) onesf[j] = (bf16_t)1.f;

    f32x4 O[2][4];
    float mi[2][4], li[2][4];
#pragma unroll
    for (int rt = 0; rt < 2; ++rt)
#pragma unroll
        for (int e = 0; e < 4; ++e) { mi[rt][e] = -1e30f; li[rt][e] = 0.f; }
#pragma unroll
    for (int rt = 0; rt < 2; ++rt)
#pragma unroll
        for (int d = 0; d < 4; ++d) O[rt][d] = fzero;

    bf16_t* const Pb = (bf16_t*)&lds[2048 + wave * 256];  // 32 qrows x 64 keys
    const int pcx = ((r >> 2) & 3) << 1;                   // P read-side chunk XOR
    const int rx  = r & 7;                                 // K read-side XOR term

    // staging: K[buf] at buf*512 in [key][chunk^key&7]; V[buf] at 1024+buf*512
#define STAGEKV(k0_, B_) { \
        const int keyl_ = tid >> 3; \
        const int kch_  = (tid & 7) ^ (keyl_ & 7); \
        const bf16_t* kp_ = kg + base + (size_t)((k0_) + keyl_) * DHEAD + kch_ * 8; \
        async_ld16(&lds[(B_) * 512 + tid], kp_); \
        async_ld16(&lds[(B_) * 512 + 256 + tid], kp_ + 32 * DHEAD); \
        const bf16_t* vp_ = vT + base + (size_t)(k0_) * DHEAD + tid * 8; \
        async_ld16(&lds[1024 + (B_) * 512 + tid], vp_); \
        async_ld16(&lds[1024 + (B_) * 512 + 256 + tid], vp_ + 2048); }

    const int NKB = 2 * qblk + 2;
    STAGEKV(0, 0);
    for (int kb = 0; kb < NKB; ++kb) {
        const int k0 = kb * 64;
        const bool pf = (kb + 1) < NKB;
        if (pf) STAGEKV((kb + 1) * 64, (kb + 1) & 1);
        if (pf) asm volatile("s_waitcnt vmcnt(4)" ::: "memory");
        else    asm volatile("s_waitcnt vmcnt(0)" ::: "memory");
        __syncthreads();

        if (k0 <= qw + 31) {   // wave-uniform: tile has >=1 unmasked key
            const int KB = (kb & 1) * 512;
            const int VB = 1024 + (kb & 1) * 512;
            f32x4 sc[2][4];
            __builtin_amdgcn_s_setprio(1);
#pragma unroll
            for (int ct = 0; ct < 4; ++ct) {
                const int kr = (ct * 16 + r) * 8;
                const bf16x8 kf0 = lds[KB + kr + (g ^ rx)];
                const bf16x8 kf1 = lds[KB + kr + ((4 + g) ^ rx)];
                sc[0][ct] = __builtin_amdgcn_mfma_f32_16x16x32_bf16(qf[0][0], kf0, fzero, 0, 0, 0);
                sc[0][ct] = __builtin_amdgcn_mfma_f32_16x16x32_bf16(qf[0][1], kf1, sc[0][ct], 0, 0, 0);
                sc[1][ct] = __builtin_amdgcn_mfma_f32_16x16x32_bf16(qf[1][0], kf0, fzero, 0, 0, 0);
                sc[1][ct] = __builtin_amdgcn_mfma_f32_16x16x32_bf16(qf[1][1], kf1, sc[1][ct], 0, 0, 0);
            }
            __builtin_amdgcn_s_setprio(0);
            if (k0 + 63 > qw) { // near-diagonal: causal mask
#pragma unroll
                for (int rt = 0; rt < 2; ++rt)
#pragma unroll
                    for (int ct = 0; ct < 4; ++ct)
#pragma unroll
                        for (int e = 0; e < 4; ++e)
                            if (k0 + ct * 16 + r > qw + rt * 16 + g * 4 + e)
                                sc[rt][ct][e] = -1e30f;
            }
            // row maxes (in-reg + 4-level shfl over r)
            float mx[2][4];
#pragma unroll
            for (int rt = 0; rt < 2; ++rt)
#pragma unroll
                for (int e = 0; e < 4; ++e) {
                    float m = fmaxf(fmaxf(sc[rt][0][e], sc[rt][1][e]),
                                    fmaxf(sc[rt][2][e], sc[rt][3][e]));
#pragma unroll
                    for (int d = 1; d < 16; d <<= 1) m = fmaxf(m, __shfl_xor(m, d));
                    mx[rt][e] = m;
                }
            // defer-max: one wave-uniform decision for all 8 rows
            float worst = mx[0][0] - mi[0][0];
#pragma unroll
            for (int rt = 0; rt < 2; ++rt)
#pragma unroll
                for (int e = 0; e < 4; ++e)
                    worst = fmaxf(worst, mx[rt][e] - mi[rt][e]);
            if (!__all(worst <= 8.f)) {
#pragma unroll
                for (int rt = 0; rt < 2; ++rt)
#pragma unroll
                    for (int e = 0; e < 4; ++e) {
                        const float mnew  = fmaxf(mi[rt][e], mx[rt][e]);
                        const float alpha = __expf(mi[rt][e] - mnew);
                        mi[rt][e] = mnew;
                        li[rt][e] *= alpha;
#pragma unroll
                        for (int dht = 0; dht < 4; ++dht) O[rt][dht][e] *= alpha;
                    }
            }
            // P = exp(sc - mi) -> LDS (bf16), banks 2-way (free)
#pragma unroll
            for (int rt = 0; rt < 2; ++rt)
#pragma unroll
                for (int e = 0; e < 4; ++e) {
                    const int qlocal = rt * 16 + g * 4 + e;
#pragma unroll
                    for (int ct = 0; ct < 4; ++ct)
                        Pb[qlocal * 64 + ((ct * 16 + r) ^ (g << 4))] =
                            (bf16_t)__expf(sc[rt][ct][e] - mi[rt][e]);
                }
            // PV + row-sum via MFMA(P, ones)
            f32x4 S[2] = {fzero, fzero};
            __builtin_amdgcn_s_setprio(1);
#pragma unroll
            for (int kt = 0; kt < 2; ++kt) {
                const int cix = (kt * 4 + g) ^ pcx;
                const bf16x8 pf0 = lds[2048 + wave * 256 + r * 8 + cix];
                const bf16x8 pf1 = lds[2048 + wave * 256 + 128 + r * 8 + cix];
#pragma unroll
                for (int dht = 0; dht < 4; ++dht) {
                    const bf16x8 vf = lds[VB + (kt * 4 + g) * 64 + dht * 16 + r];
                    O[0][dht] = __builtin_amdgcn_mfma_f32_16x16x32_bf16(pf0, vf, O[0][dht], 0, 0, 0);
                    O[1][dht] = __builtin_amdgcn_mfma_f32_16x16x32_bf16(pf1, vf, O[1][dht], 0, 0, 0);
                }
                S[0] = __builtin_amdgcn_mfma_f32_16x16x32_bf16(pf0, onesf, S[0], 0, 0, 0);
                S[1] = __builtin_amdgcn_mfma_f32_16x16x32_bf16(pf1, onesf, S[1], 0, 0, 0);
            }
            __builtin_amdgcn_s_setprio(0);
#pragma unroll
            for (int rt = 0; rt < 2; ++rt)
#pragma unroll
                for (int e = 0; e < 4; ++e) li[rt][e] += S[rt][e];
        }
        __syncthreads();
    }
#undef STAGEKV

    const int b = bh >> 4, head = bh & 15;
#pragma unroll
    for (int rt = 0; rt < 2; ++rt) {
#pragma unroll
        for (int e = 0; e < 4; ++e) {
            const float inv = __builtin_amdgcn_rcpf(li[rt][e]);
            const int s = qw + rt * 16 + g * 4 + e;
            bf16_t* op = ctx + ((size_t)(b * SEQ + s)) * D_MODEL + head * DHEAD + r;
#pragma unroll
            for (int dht = 0; dht < 4; ++dht)
                op[dht * 16] = (bf16_t)(O[rt][dht][e] * inv);
        }
    }
}

// ---------------------------------------------------------------------------
extern "C" void kernel_launch(void* const* d_in, const int* in_sizes, int n_in,
                              void* d_out, int out_size, void* d_ws, size_t ws_size,
                              hipStream_t stream)
{
    (void)in_sizes; (void)n_in; (void)out_size; (void)ws_size;
    const float* x  = (const float*)d_in[0];
    const float* g1 = (const float*)d_in[2];
    const float* g2 = (const float*)d_in[3];
    const float* wq = (const float*)d_in[4];
    const float* wk = (const float*)d_in[5];
    const float* wv = (const float*)d_in[6];
    const float* wo = (const float*)d_in[7];
    const float* w1 = (const float*)d_in[8];
    const float* w2 = (const float*)d_in[9];
    const float* w3 = (const float*)d_in[10];
    float* out = (float*)d_out;
    char* ws = (char*)d_ws;
    const size_t MB = 1ull << 20;
    bf16_t* wqkvT = (bf16_t*)(ws + 0);        // 3072 x 1024
    bf16_t* woT   = (bf16_t*)(ws + 6  * MB);  // 1024 x 1024
    bf16_t* w13T  = (bf16_t*)(ws + 8  * MB);  // 8192 x 1024 (16-col-group ilv)
    bf16_t* w2T   = (bf16_t*)(ws + 24 * MB);  // 1024 x 4096
    bf16_t* hbuf  = (bf16_t*)(ws + 32 * MB);  // h / h2; reused as vT during attn
    bf16_t* qbuf  = (bf16_t*)(ws + 48 * MB);
    bf16_t* kbuf  = (bf16_t*)(ws + 64 * MB);
    bf16_t* vbuf  = (bf16_t*)(ws + 80 * MB);
    bf16_t* ctx   = (bf16_t*)(ws + 96 * MB);
    bf16_t* gate  = (bf16_t*)(ws + 48 * MB);  // 8192 x 4096, reuses q/k/v/ctx
    bf16_t* vTb   = hbuf;                     // tiled [bh][kc][dh][8]

    dim3 blk(256);
    dim3 blk5(512);
    transpose_cast_kernel<<<dim3(32, 32),  blk, 0, stream>>>(wq, wqkvT,             1024, 1024, 16, 0);
    transpose_cast_kernel<<<dim3(32, 32),  blk, 0, stream>>>(wk, wqkvT + 1024*1024, 1024, 1024, 16, 0);
    transpose_cast_kernel<<<dim3(32, 32),  blk, 0, stream>>>(wv, wqkvT + 2048*1024, 1024, 1024, 16, 0);
    transpose_cast_kernel<<<dim3(32, 32),  blk, 0, stream>>>(wo, woT,               1024, 1024, 16, 0);
    transpose_cast_kernel<<<dim3(128, 32), blk, 0, stream>>>(w1, w13T,              1024, 4096, 32, 0);
    transpose_cast_kernel<<<dim3(128, 32), blk, 0, stream>>>(w3, w13T,              1024, 4096, 32, 16);
    transpose_cast_kernel<<<dim3(32, 128), blk, 0, stream>>>(w2, w2T,               4096, 1024, 16, 0);

    rmsnorm_kernel<<<dim3(8192), blk, 0, stream>>>(x, g1, hbuf);

    gemm256_kernel<0><<<dim3(12, 32), blk5, 0, stream>>>(hbuf, wqkvT, 8192, 3072, 1024,
        qbuf, kbuf, vbuf, nullptr);

    transpose_v_kernel<<<dim3(32, 64), blk, 0, stream>>>(vbuf, vTb);

    attn_kernel<<<dim3(1024), blk, 0, stream>>>(qbuf, kbuf, vTb, ctx);

    gemm128_kernel<1><<<dim3(8, 64), blk, 0, stream>>>(ctx, woT, 8192, 1024, 1024, x, out);

    rmsnorm_kernel<<<dim3(8192), blk, 0, stream>>>(out, g2, hbuf);

    gemm256_kernel<2><<<dim3(32, 32), blk5, 0, stream>>>(hbuf, w13T, 8192, 8192, 1024,
        nullptr, nullptr, nullptr, gate);

    gemm128_kernel<3><<<dim3(8, 64), blk, 0, stream>>>(gate, w2T, 8192, 1024, 4096, out, out);
}

// Round 8
// 576.831 us; speedup vs baseline: 1.2122x; 1.0382x over previous
//
#include <hip/hip_runtime.h>
#include <hip/hip_bf16.h>
#include <cstdint>
#include <cstddef>

typedef __bf16 bf16_t;
typedef __bf16 bf16x8 __attribute__((ext_vector_type(8)));
typedef __bf16 bf16x4 __attribute__((ext_vector_type(4)));
typedef float  f32x4  __attribute__((ext_vector_type(4)));

#define D_MODEL 1024
#define SEQ     2048
#define NHEADS  16
#define DHEAD   64
#define DFF     4096

// async global->LDS, 16B per lane; lds base must be wave-uniform (dest = base + lane*16)
__device__ __forceinline__ void async_ld16(void* lds, const void* g) {
    __builtin_amdgcn_global_load_lds(
        (__attribute__((address_space(1))) void*)(void*)(g),
        (__attribute__((address_space(3))) void*)(lds), 16, 0, 0);
}

// Resident-operand XCD swizzle: XCD x owns by-chunk [x*cy, (x+1)*cy) which
// stays L2-resident; bx sweeps. Requires gridDim.y % 8 == 0 (bijective).
__device__ __forceinline__ void xcd_swizzle(int& bx, int& by) {
    const int gy = gridDim.y;
    const int i = blockIdx.x + gridDim.x * blockIdx.y;
    if ((gy & 7) == 0) {
        const int cy = gy >> 3;
        const int xcd = i & 7, j = i >> 3;
        bx = j / cy;
        by = xcd * cy + (j % cy);
    } else { bx = blockIdx.x; by = blockIdx.y; }
}

// ---------------------------------------------------------------------------
// fp32 (K x N) -> bf16 transposed; dst row for source col n:
//   (n>>4)*gstride + (n&15) + goff
// ---------------------------------------------------------------------------
__global__ __launch_bounds__(256)
void transpose_cast_kernel(const float* __restrict__ src, bf16_t* __restrict__ dst,
                           int K, int N, int gstride, int goff)
{
    __shared__ float tile[32][33];
    const int bn = blockIdx.x * 32, bk = blockIdx.y * 32;
    const int tx = threadIdx.x & 31, ty = threadIdx.x >> 5;
#pragma unroll
    for (int i = 0; i < 32; i += 8)
        tile[ty + i][tx] = src[(size_t)(bk + ty + i) * N + bn + tx];
    __syncthreads();
#pragma unroll
    for (int i = 0; i < 32; i += 8) {
        const int n = bn + ty + i, kk = bk + tx;
        const int row = (n >> 4) * gstride + (n & 15) + goff;
        dst[(size_t)row * K + kk] = (bf16_t)tile[tx][ty + i];
    }
}

// ---------------------------------------------------------------------------
// bf16 V [bh][s][dh] -> vT tiled [bh][kc=s/8][dh][8] (so attn V-staging is a
// LINEAR global_load_lds stream).
// ---------------------------------------------------------------------------
__global__ __launch_bounds__(256)
void transpose_v_kernel(const bf16_t* __restrict__ v, bf16_t* __restrict__ vt)
{
    __shared__ bf16_t T[64 * 66];
    const int bh = blockIdx.y, s0 = blockIdx.x * 64;
    const int tid = threadIdx.x;
    const size_t vb = (size_t)bh * SEQ * DHEAD;
#pragma unroll
    for (int h = 0; h < 2; ++h) {
        const int s = h * 32 + (tid >> 3), dc = (tid & 7) * 8;
        const bf16x8 vv = *(const bf16x8*)(v + vb + (size_t)(s0 + s) * DHEAD + dc);
#pragma unroll
        for (int j = 0; j < 8; ++j) T[(dc + j) * 66 + s] = vv[j];
    }
    __syncthreads();
    const size_t tb = (size_t)bh * DHEAD * SEQ;
    const uint32_t* Tw = (const uint32_t*)T;
#pragma unroll
    for (int h = 0; h < 2; ++h) {
        const int dh = h * 32 + (tid >> 3), kc = (tid & 7) * 8;
        uint4 o;
        o.x = Tw[dh * 33 + kc / 2 + 0];
        o.y = Tw[dh * 33 + kc / 2 + 1];
        o.z = Tw[dh * 33 + kc / 2 + 2];
        o.w = Tw[dh * 33 + kc / 2 + 3];
        // tiled dst: [kcg][dh][8], kcg = (s0+kc)/8
        *(uint4*)(vt + tb + (size_t)((s0 + kc) >> 3) * 512 + dh * 8) = o;
    }
}

// ---------------------------------------------------------------------------
// RMSNorm: fp32 row (1024) -> bf16 row
// ---------------------------------------------------------------------------
__global__ __launch_bounds__(256)
void rmsnorm_kernel(const float* __restrict__ x, const float* __restrict__ gw,
                    bf16_t* __restrict__ out)
{
    const int row = blockIdx.x, tid = threadIdx.x;
    const float4 v = ((const float4*)(x + (size_t)row * D_MODEL))[tid];
    float ss = v.x*v.x + v.y*v.y + v.z*v.z + v.w*v.w;
#pragma unroll
    for (int d = 1; d < 64; d <<= 1) ss += __shfl_xor(ss, d);
    __shared__ float red[4];
    if ((tid & 63) == 0) red[tid >> 6] = ss;
    __syncthreads();
    const float tot = red[0] + red[1] + red[2] + red[3];
    const float sc = rsqrtf(tot * (1.f / D_MODEL) + 1e-5f);
    const float4 gv = ((const float4*)gw)[tid];
    bf16x4 o;
    o[0] = (bf16_t)(v.x * sc * gv.x);
    o[1] = (bf16_t)(v.y * sc * gv.y);
    o[2] = (bf16_t)(v.z * sc * gv.z);
    o[3] = (bf16_t)(v.w * sc * gv.w);
    ((bf16x4*)(out + (size_t)row * D_MODEL))[tid] = o;
}

// ---------------------------------------------------------------------------
// 256x256 GEMM, coalesced staging + bank-correct XOR swizzle.
// LDS [256 rows][8 chunks] of bf16x8; physical chunk p = c ^ (row&7) applied
// on the global source addr (LDS dest linear) and on ds_read chunk index.
// Row stride = 128B = one bank sweep, so the bank quad is p alone; XORing
// the LOW 3 row bits makes every 8-consecutive-lane group hit 8 distinct
// quads -> conflict-free (the r>>2-bit variant was a 4-way conflict).
// ---------------------------------------------------------------------------
template <int MODE>
__global__ __launch_bounds__(512, 2)
void gemm256_kernel(const bf16_t* __restrict__ A, const bf16_t* __restrict__ Bt,
                    int M, int N, int K,
                    bf16_t* __restrict__ qo, bf16_t* __restrict__ ko, bf16_t* __restrict__ vo,
                    bf16_t* __restrict__ gate)
{
    __shared__ bf16x8 lds[8192];   // 128 KB
    const int tid  = threadIdx.x;
    const int wave = tid >> 6;
    const int lane = tid & 63;
    const int r = lane & 15, g = lane >> 4;
    const int wm = wave >> 2;
    const int wn = wave & 3;
    const int rx  = r & 7;
    const int cx0 = g ^ rx;            // chunk term ks=0
    const int cx1 = cx0 ^ 4;           // chunk term ks=1

    int bx, by;
    xcd_swizzle(bx, by);
    const int row0 = by * 256;
    const int col0 = bx * 256;

    const f32x4 fzero = {0.f, 0.f, 0.f, 0.f};
    f32x4 acc[8][4];
#pragma unroll
    for (int i = 0; i < 8; ++i)
#pragma unroll
        for (int j = 0; j < 4; ++j) acc[i][j] = fzero;

    const int kcx = ((tid & 7) ^ ((tid >> 3) & 7)) * 8;
    const bf16_t* aSrc = A  + (size_t)(row0 + (tid >> 3)) * K + kcx;
    const bf16_t* bSrc = Bt + (size_t)(col0 + (tid >> 3)) * K + kcx;

    const int aRB = wm * 1024 + r * 8;
    const int bRB = 2048 + wn * 512 + r * 8;

#define STA(nb, ktn, h_, j_) \
    async_ld16(&lds[(nb) + (h_) * 1024 + (j_) * 512 + tid], \
               aSrc + (size_t)((h_) * 128 + (j_) * 64) * K + (ktn))
#define STB(nb, ktn, h_, j_) \
    async_ld16(&lds[(nb) + 2048 + (h_) * 1024 + (j_) * 512 + tid], \
               bSrc + (size_t)((h_) * 128 + (j_) * 64) * K + (ktn))

    STB(0, 0, 0, 0); STB(0, 0, 0, 1); STB(0, 0, 1, 0); STB(0, 0, 1, 1);
    STA(0, 0, 0, 0); STA(0, 0, 1, 0);
    STA(0, 0, 0, 1); STA(0, 0, 1, 1);
    asm volatile("s_waitcnt vmcnt(2)" ::: "memory");
    __builtin_amdgcn_s_barrier();

    bf16x8 aF[8], bF[8];

    const int NT = K >> 6;
    for (int t = 0; t < NT; ++t) {
        const int AB  = (t & 1) << 12;
        const int nb  = AB ^ 4096;
        const int ktn = (t + 1) << 6;
        const bool pf = (t + 1) < NT;

        // ---- phase 0: quad (mh0, nh0) ----
#pragma unroll
        for (int q = 0; q < 4; ++q) {
            aF[q * 2 + 0] = lds[AB + aRB + q * 128 + cx0];
            aF[q * 2 + 1] = lds[AB + aRB + q * 128 + cx1];
        }
#pragma unroll
        for (int n = 0; n < 2; ++n) {
            bF[n * 2 + 0] = lds[AB + bRB + n * 128 + cx0];
            bF[n * 2 + 1] = lds[AB + bRB + n * 128 + cx1];
        }
        if (pf) { STB(nb, ktn, 0, 0); STB(nb, ktn, 0, 1); }
        __builtin_amdgcn_s_barrier();
        asm volatile("s_waitcnt lgkmcnt(0)" ::: "memory");
        __builtin_amdgcn_sched_barrier(0);
        __builtin_amdgcn_s_setprio(1);
#pragma unroll
        for (int q = 0; q < 4; ++q)
#pragma unroll
            for (int n = 0; n < 2; ++n)
#pragma unroll
                for (int ks = 0; ks < 2; ++ks)
                    acc[q][n] = __builtin_amdgcn_mfma_f32_16x16x32_bf16(
                        aF[q * 2 + ks], bF[n * 2 + ks], acc[q][n], 0, 0, 0);
        __builtin_amdgcn_s_setprio(0);
        __builtin_amdgcn_s_barrier();

        // ---- phase 1: quad (mh0, nh1) ----
#pragma unroll
        for (int n = 0; n < 2; ++n) {
            bF[4 + n * 2 + 0] = lds[AB + bRB + (32 + n * 16) * 8 + cx0];
            bF[4 + n * 2 + 1] = lds[AB + bRB + (32 + n * 16) * 8 + cx1];
        }
        if (pf) { STB(nb, ktn, 1, 0); STB(nb, ktn, 1, 1); }
        __builtin_amdgcn_s_barrier();
        asm volatile("s_waitcnt lgkmcnt(0)" ::: "memory");
        __builtin_amdgcn_sched_barrier(0);
        __builtin_amdgcn_s_setprio(1);
#pragma unroll
        for (int q = 0; q < 4; ++q)
#pragma unroll
            for (int n = 0; n < 2; ++n)
#pragma unroll
                for (int ks = 0; ks < 2; ++ks)
                    acc[q][2 + n] = __builtin_amdgcn_mfma_f32_16x16x32_bf16(
                        aF[q * 2 + ks], bF[4 + n * 2 + ks], acc[q][2 + n], 0, 0, 0);
        __builtin_amdgcn_s_setprio(0);
        if (pf) asm volatile("s_waitcnt vmcnt(4)" ::: "memory");
        else    asm volatile("s_waitcnt vmcnt(0)" ::: "memory");
        __builtin_amdgcn_s_barrier();

        // ---- phase 2: quad (mh1, nh1) ----
#pragma unroll
        for (int q = 0; q < 4; ++q) {
            aF[q * 2 + 0] = lds[AB + aRB + (64 + q * 16) * 8 + cx0];
            aF[q * 2 + 1] = lds[AB + aRB + (64 + q * 16) * 8 + cx1];
        }
        if (pf) { STA(nb, ktn, 0, 0); STA(nb, ktn, 1, 0); }
        __builtin_amdgcn_s_barrier();
        asm volatile("s_waitcnt lgkmcnt(0)" ::: "memory");
        __builtin_amdgcn_sched_barrier(0);
        __builtin_amdgcn_s_setprio(1);
#pragma unroll
        for (int q = 0; q < 4; ++q)
#pragma unroll
            for (int n = 0; n < 2; ++n)
#pragma unroll
                for (int ks = 0; ks < 2; ++ks)
                    acc[4 + q][2 + n] = __builtin_amdgcn_mfma_f32_16x16x32_bf16(
                        aF[q * 2 + ks], bF[4 + n * 2 + ks], acc[4 + q][2 + n], 0, 0, 0);
        __builtin_amdgcn_s_setprio(0);
        __builtin_amdgcn_s_barrier();

        // ---- phase 3: quad (mh1, nh0) ----
        if (pf) { STA(nb, ktn, 0, 1); STA(nb, ktn, 1, 1); }
        __builtin_amdgcn_s_barrier();
        __builtin_amdgcn_s_setprio(1);
#pragma unroll
        for (int q = 0; q < 4; ++q)
#pragma unroll
            for (int n = 0; n < 2; ++n)
#pragma unroll
                for (int ks = 0; ks < 2; ++ks)
                    acc[4 + q][n] = __builtin_amdgcn_mfma_f32_16x16x32_bf16(
                        aF[q * 2 + ks], bF[n * 2 + ks], acc[4 + q][n], 0, 0, 0);
        __builtin_amdgcn_s_setprio(0);
        if (pf) asm volatile("s_waitcnt vmcnt(2)" ::: "memory");
        __builtin_amdgcn_s_barrier();
    }
#undef STA
#undef STB

    const int mbase = row0 + wm * 128 + g * 4;
    const int nbase = col0 + wn * 64 + r;

    if constexpr (MODE == 2) {
#pragma unroll
        for (int np = 0; np < 2; ++np) {
            const int gc = (col0 >> 1) + wn * 32 + np * 16 + r;
#pragma unroll
            for (int mt = 0; mt < 8; ++mt) {
#pragma unroll
                for (int e = 0; e < 4; ++e) {
                    const float v1 = acc[mt][2 * np][e];
                    const float v3 = acc[mt][2 * np + 1][e];
                    const float sv = v1 * __builtin_amdgcn_rcpf(1.f + __expf(-v1));
                    const int grow = mbase + mt * 16 + e;
                    gate[(size_t)grow * DFF + gc] = (bf16_t)(sv * v3);
                }
            }
        }
    } else { // MODE 0
#pragma unroll
        for (int nt = 0; nt < 4; ++nt) {
            const int gcol = nbase + nt * 16;
            const int mat  = gcol >> 10;
            const int d    = gcol & 1023;
            const int head = d >> 6;
            const int dh   = d & 63;
            const float invf = __expf((float)(dh & ~1) * -0.14391157f);
            const size_t hb = (size_t)head * SEQ * DHEAD + dh;
#pragma unroll
            for (int mt = 0; mt < 8; ++mt) {
#pragma unroll
                for (int e = 0; e < 4; ++e) {
                    const float val = acc[mt][nt][e];
                    const float partner = __shfl_xor(val, 1);
                    const int grow = mbase + mt * 16 + e;
                    const int b = grow >> 11;
                    const int s = grow & 2047;
                    const size_t dst = (size_t)b * NHEADS * SEQ * DHEAD + hb + (size_t)s * DHEAD;
                    if (mat == 2) {
                        vo[dst] = (bf16_t)val;
                    } else {
                        float sn, cs;
                        __sincosf((float)s * invf, &sn, &cs);
                        const float rv = (dh & 1) ? (partner * sn + val * cs)
                                                  : (val * cs - partner * sn);
                        if (mat == 0) qo[dst] = (bf16_t)(rv * 0.125f);
                        else          ko[dst] = (bf16_t)rv;
                    }
                }
            }
        }
    }
}

// ---------------------------------------------------------------------------
// 128x128 GEMM (4 waves, 3 blocks/CU), bank-correct XOR swizzle (row&7).
// MODE 1/3: out = res + C (fp32, res may alias outf).
// ---------------------------------------------------------------------------
template <int MODE>
__global__ __launch_bounds__(256, 3)
void gemm128_kernel(const bf16_t* __restrict__ A, const bf16_t* __restrict__ Bt,
                    int M, int N, int K, const float* res, float* outf)
{
    __shared__ bf16x8 Al[1024];
    __shared__ bf16x8 Bl[1024];
    const int tid  = threadIdx.x;
    const int wave = tid >> 6;
    const int lane = tid & 63;
    const int r    = lane & 15;
    const int g    = lane >> 4;
    const int wm   = wave >> 1;
    const int wn   = wave & 1;
    const int rx   = r & 7;
    const int cx0 = g ^ rx;
    const int cx1 = cx0 ^ 4;

    int bx, by;
    xcd_swizzle(bx, by);
    const int row0 = by * 128;
    const int col0 = bx * 128;

    const f32x4 fzero = {0.f, 0.f, 0.f, 0.f};
    f32x4 acc[4][4];
#pragma unroll
    for (int i = 0; i < 4; ++i)
#pragma unroll
        for (int j = 0; j < 4; ++j) acc[i][j] = fzero;

    const int kcx = ((tid & 7) ^ ((tid >> 3) & 7)) * 8;
    const bf16_t* a0 = A  + (size_t)(row0 + (tid >> 3)) * K + kcx;
    const bf16_t* b0 = Bt + (size_t)(col0 + (tid >> 3)) * K + kcx;

    for (int kt = 0; kt < K; kt += 64) {
#pragma unroll
        for (int j = 0; j < 4; ++j)
            async_ld16(&Al[j * 256 + tid], a0 + kt + (size_t)(j * 32) * K);
#pragma unroll
        for (int j = 0; j < 4; ++j)
            async_ld16(&Bl[j * 256 + tid], b0 + kt + (size_t)(j * 32) * K);
        __syncthreads();
#pragma unroll
        for (int s = 0; s < 2; ++s) {
            const int cx = s ? cx1 : cx0;
            bf16x8 af[4], bfr[4];
#pragma unroll
            for (int mt = 0; mt < 4; ++mt) af[mt]  = Al[(wm * 64 + mt * 16 + r) * 8 + cx];
#pragma unroll
            for (int nt = 0; nt < 4; ++nt) bfr[nt] = Bl[(wn * 64 + nt * 16 + r) * 8 + cx];
#pragma unroll
            for (int mt = 0; mt < 4; ++mt)
#pragma unroll
                for (int nt = 0; nt < 4; ++nt)
                    acc[mt][nt] = __builtin_amdgcn_mfma_f32_16x16x32_bf16(
                        af[mt], bfr[nt], acc[mt][nt], 0, 0, 0);
        }
        __syncthreads();
    }

    const int mbase = row0 + wm * 64 + g * 4;
    const int nbase = col0 + wn * 64 + r;
#pragma unroll
    for (int mt = 0; mt < 4; ++mt) {
#pragma unroll
        for (int nt = 0; nt < 4; ++nt) {
#pragma unroll
            for (int e = 0; e < 4; ++e) {
                const int grow = mbase + mt * 16 + e;
                const int gcol = nbase + nt * 16;
                const size_t idx = (size_t)grow * D_MODEL + gcol;
                outf[idx] = res[idx] + acc[mt][nt][e];
            }
        }
    }
}

// ---------------------------------------------------------------------------
// Causal flash attention. (unchanged round-7 winner)
// ---------------------------------------------------------------------------
__global__ __launch_bounds__(256, 3)
void attn_kernel(const bf16_t* __restrict__ qg, const bf16_t* __restrict__ kg,
                 const bf16_t* __restrict__ vT, bf16_t* __restrict__ ctx)
{
    __shared__ bf16x8 lds[3072];   // K0 K1 V0 V1 : 512 each, P 1024
    const int qblk = 15 - (blockIdx.x >> 6);
    const int bh   = blockIdx.x & 63;
    const int tid  = threadIdx.x;
    const int wave = tid >> 6;
    const int lane = tid & 63;
    const int r = lane & 15, g = lane >> 4;
    const size_t base = (size_t)bh * SEQ * DHEAD;
    const int qw = qblk * 128 + wave * 32;

    bf16x8 qf[2][2];
#pragma unroll
    for (int rt = 0; rt < 2; ++rt)
#pragma unroll
        for (int kh = 0; kh < 2; ++kh)
            qf[rt][kh] = *(const bf16x8*)(qg + base + (size_t)(qw + rt*16 + r) * DHEAD + kh*32 + g*8);

    const f32x4 fzero = {0.f, 0.f, 0.f, 0.f};
    bf16x8 onesf;
#pragma unroll
    for (int j = 0; j < 8; ++j) onesf[j] = (bf16_t)1.f;

    f32x4 O[2][4];
    float mi[2][4], li[2][4];
#pragma unroll
    for (int rt = 0; rt < 2; ++rt)
#pragma unroll
        for (int e = 0; e < 4; ++e) { mi[rt][e] = -1e30f; li[rt][e] = 0.f; }
#pragma unroll
    for (int rt = 0; rt < 2; ++rt)
#pragma unroll
        for (int d = 0; d < 4; ++d) O[rt][d] = fzero;

    bf16_t* const Pb = (bf16_t*)&lds[2048 + wave * 256];  // 32 qrows x 64 keys
    const int pcx = ((r >> 2) & 3) << 1;                   // P read-side chunk XOR
    const int rx  = r & 7;                                 // K read-side XOR term

    // staging: K[buf] at buf*512 in [key][chunk^key&7]; V[buf] at 1024+buf*512
#define STAGEKV(k0_, B_) { \
        const int keyl_ = tid >> 3; \
        const int kch_  = (tid & 7) ^ (keyl_ & 7); \
        const bf16_t* kp_ = kg + base + (size_t)((k0_) + keyl_) * DHEAD + kch_ * 8; \
        async_ld16(&lds[(B_) * 512 + tid], kp_); \
        async_ld16(&lds[(B_) * 512 + 256 + tid], kp_ + 32 * DHEAD); \
        const bf16_t* vp_ = vT + base + (size_t)(k0_) * DHEAD + tid * 8; \
        async_ld16(&lds[1024 + (B_) * 512 + tid], vp_); \
        async_ld16(&lds[1024 + (B_) * 512 + 256 + tid], vp_ + 2048); }

    const int NKB = 2 * qblk + 2;
    STAGEKV(0, 0);
    for (int kb = 0; kb < NKB; ++kb) {
        const int k0 = kb * 64;
        const bool pf = (kb + 1) < NKB;
        if (pf) STAGEKV((kb + 1) * 64, (kb + 1) & 1);
        if (pf) asm volatile("s_waitcnt vmcnt(4)" ::: "memory");
        else    asm volatile("s_waitcnt vmcnt(0)" ::: "memory");
        __syncthreads();

        if (k0 <= qw + 31) {   // wave-uniform: tile has >=1 unmasked key
            const int KB = (kb & 1) * 512;
            const int VB = 1024 + (kb & 1) * 512;
            f32x4 sc[2][4];
            __builtin_amdgcn_s_setprio(1);
#pragma unroll
            for (int ct = 0; ct < 4; ++ct) {
                const int kr = (ct * 16 + r) * 8;
                const bf16x8 kf0 = lds[KB + kr + (g ^ rx)];
                const bf16x8 kf1 = lds[KB + kr + ((4 + g) ^ rx)];
                sc[0][ct] = __builtin_amdgcn_mfma_f32_16x16x32_bf16(qf[0][0], kf0, fzero, 0, 0, 0);
                sc[0][ct] = __builtin_amdgcn_mfma_f32_16x16x32_bf16(qf[0][1], kf1, sc[0][ct], 0, 0, 0);
                sc[1][ct] = __builtin_amdgcn_mfma_f32_16x16x32_bf16(qf[1][0], kf0, fzero, 0, 0, 0);
                sc[1][ct] = __builtin_amdgcn_mfma_f32_16x16x32_bf16(qf[1][1], kf1, sc[1][ct], 0, 0, 0);
            }
            __builtin_amdgcn_s_setprio(0);
            if (k0 + 63 > qw) { // near-diagonal: causal mask
#pragma unroll
                for (int rt = 0; rt < 2; ++rt)
#pragma unroll
                    for (int ct = 0; ct < 4; ++ct)
#pragma unroll
                        for (int e = 0; e < 4; ++e)
                            if (k0 + ct * 16 + r > qw + rt * 16 + g * 4 + e)
                                sc[rt][ct][e] = -1e30f;
            }
            // row maxes (in-reg + 4-level shfl over r)
            float mx[2][4];
#pragma unroll
            for (int rt = 0; rt < 2; ++rt)
#pragma unroll
                for (int e = 0; e < 4; ++e) {
                    float m = fmaxf(fmaxf(sc[rt][0][e], sc[rt][1][e]),
                                    fmaxf(sc[rt][2][e], sc[rt][3][e]));
#pragma unroll
                    for (int d = 1; d < 16; d <<= 1) m = fmaxf(m, __shfl_xor(m, d));
                    mx[rt][e] = m;
                }
            // defer-max: one wave-uniform decision for all 8 rows
            float worst = mx[0][0] - mi[0][0];
#pragma unroll
            for (int rt = 0; rt < 2; ++rt)
#pragma unroll
                for (int e = 0; e < 4; ++e)
                    worst = fmaxf(worst, mx[rt][e] - mi[rt][e]);
            if (!__all(worst <= 8.f)) {
#pragma unroll
                for (int rt = 0; rt < 2; ++rt)
#pragma unroll
                    for (int e = 0; e < 4; ++e) {
                        const float mnew  = fmaxf(mi[rt][e], mx[rt][e]);
                        const float alpha = __expf(mi[rt][e] - mnew);
                        mi[rt][e] = mnew;
                        li[rt][e] *= alpha;
#pragma unroll
                        for (int dht = 0; dht < 4; ++dht) O[rt][dht][e] *= alpha;
                    }
            }
            // P = exp(sc - mi) -> LDS (bf16), banks 2-way (free)
#pragma unroll
            for (int rt = 0; rt < 2; ++rt)
#pragma unroll
                for (int e = 0; e < 4; ++e) {
                    const int qlocal = rt * 16 + g * 4 + e;
#pragma unroll
                    for (int ct = 0; ct < 4; ++ct)
                        Pb[qlocal * 64 + ((ct * 16 + r) ^ (g << 4))] =
                            (bf16_t)__expf(sc[rt][ct][e] - mi[rt][e]);
                }
            // PV + row-sum via MFMA(P, ones)
            f32x4 S[2] = {fzero, fzero};
            __builtin_amdgcn_s_setprio(1);
#pragma unroll
            for (int kt = 0; kt < 2; ++kt) {
                const int cix = (kt * 4 + g) ^ pcx;
                const bf16x8 pf0 = lds[2048 + wave * 256 + r * 8 + cix];
                const bf16x8 pf1 = lds[2048 + wave * 256 + 128 + r * 8 + cix];
#pragma unroll
                for (int dht = 0; dht < 4; ++dht) {
                    const bf16x8 vf = lds[VB + (kt * 4 + g) * 64 + dht * 16 + r];
                    O[0][dht] = __builtin_amdgcn_mfma_f32_16x16x32_bf16(pf0, vf, O[0][dht], 0, 0, 0);
                    O[1][dht] = __builtin_amdgcn_mfma_f32_16x16x32_bf16(pf1, vf, O[1][dht], 0, 0, 0);
                }
                S[0] = __builtin_amdgcn_mfma_f32_16x16x32_bf16(pf0, onesf, S[0], 0, 0, 0);
                S[1] = __builtin_amdgcn_mfma_f32_16x16x32_bf16(pf1, onesf, S[1], 0, 0, 0);
            }
            __builtin_amdgcn_s_setprio(0);
#pragma unroll
            for (int rt = 0; rt < 2; ++rt)
#pragma unroll
                for (int e = 0; e < 4; ++e) li[rt][e] += S[rt][e];
        }
        __syncthreads();
    }
#undef STAGEKV

    const int b = bh >> 4, head = bh & 15;
#pragma unroll
    for (int rt = 0; rt < 2; ++rt) {
#pragma unroll
        for (int e = 0; e < 4; ++e) {
            const float inv = __builtin_amdgcn_rcpf(li[rt][e]);
            const int s = qw + rt * 16 + g * 4 + e;
            bf16_t* op = ctx + ((size_t)(b * SEQ + s)) * D_MODEL + head * DHEAD + r;
#pragma unroll
            for (int dht = 0; dht < 4; ++dht)
                op[dht * 16] = (bf16_t)(O[rt][dht][e] * inv);
        }
    }
}

// ---------------------------------------------------------------------------
extern "C" void kernel_launch(void* const* d_in, const int* in_sizes, int n_in,
                              void* d_out, int out_size, void* d_ws, size_t ws_size,
                              hipStream_t stream)
{
    (void)in_sizes; (void)n_in; (void)out_size; (void)ws_size;
    const float* x  = (const float*)d_in[0];
    const float* g1 = (const float*)d_in[2];
    const float* g2 = (const float*)d_in[3];
    const float* wq = (const float*)d_in[4];
    const float* wk = (const float*)d_in[5];
    const float* wv = (const float*)d_in[6];
    const float* wo = (const float*)d_in[7];
    const float* w1 = (const float*)d_in[8];
    const float* w2 = (const float*)d_in[9];
    const float* w3 = (const float*)d_in[10];
    float* out = (float*)d_out;
    char* ws = (char*)d_ws;
    const size_t MB = 1ull << 20;
    bf16_t* wqkvT = (bf16_t*)(ws + 0);        // 3072 x 1024
    bf16_t* woT   = (bf16_t*)(ws + 6  * MB);  // 1024 x 1024
    bf16_t* w13T  = (bf16_t*)(ws + 8  * MB);  // 8192 x 1024 (16-col-group ilv)
    bf16_t* w2T   = (bf16_t*)(ws + 24 * MB);  // 1024 x 4096
    bf16_t* hbuf  = (bf16_t*)(ws + 32 * MB);  // h / h2; reused as vT during attn
    bf16_t* qbuf  = (bf16_t*)(ws + 48 * MB);
    bf16_t* kbuf  = (bf16_t*)(ws + 64 * MB);
    bf16_t* vbuf  = (bf16_t*)(ws + 80 * MB);
    bf16_t* ctx   = (bf16_t*)(ws + 96 * MB);
    bf16_t* gate  = (bf16_t*)(ws + 48 * MB);  // 8192 x 4096, reuses q/k/v/ctx
    bf16_t* vTb   = hbuf;                     // tiled [bh][kc][dh][8]

    dim3 blk(256);
    dim3 blk5(512);
    transpose_cast_kernel<<<dim3(32, 32),  blk, 0, stream>>>(wq, wqkvT,             1024, 1024, 16, 0);
    transpose_cast_kernel<<<dim3(32, 32),  blk, 0, stream>>>(wk, wqkvT + 1024*1024, 1024, 1024, 16, 0);
    transpose_cast_kernel<<<dim3(32, 32),  blk, 0, stream>>>(wv, wqkvT + 2048*1024, 1024, 1024, 16, 0);
    transpose_cast_kernel<<<dim3(32, 32),  blk, 0, stream>>>(wo, woT,               1024, 1024, 16, 0);
    transpose_cast_kernel<<<dim3(128, 32), blk, 0, stream>>>(w1, w13T,              1024, 4096, 32, 0);
    transpose_cast_kernel<<<dim3(128, 32), blk, 0, stream>>>(w3, w13T,              1024, 4096, 32, 16);
    transpose_cast_kernel<<<dim3(32, 128), blk, 0, stream>>>(w2, w2T,               4096, 1024, 16, 0);

    rmsnorm_kernel<<<dim3(8192), blk, 0, stream>>>(x, g1, hbuf);

    gemm256_kernel<0><<<dim3(12, 32), blk5, 0, stream>>>(hbuf, wqkvT, 8192, 3072, 1024,
        qbuf, kbuf, vbuf, nullptr);

    transpose_v_kernel<<<dim3(32, 64), blk, 0, stream>>>(vbuf, vTb);

    attn_kernel<<<dim3(1024), blk, 0, stream>>>(qbuf, kbuf, vTb, ctx);

    gemm128_kernel<1><<<dim3(8, 64), blk, 0, stream>>>(ctx, woT, 8192, 1024, 1024, x, out);

    rmsnorm_kernel<<<dim3(8192), blk, 0, stream>>>(out, g2, hbuf);

    gemm256_kernel<2><<<dim3(32, 32), blk5, 0, stream>>>(hbuf, w13T, 8192, 8192, 1024,
        nullptr, nullptr, nullptr, gate);

    gemm128_kernel<3><<<dim3(8, 64), blk, 0, stream>>>(gate, w2T, 8192, 1024, 4096, out, out);
}